// Round 5
// baseline (62700.995 us; speedup 1.0000x reference)
//
#include <hip/hip_runtime.h>

// ---------------- workspace layout (float units), total ~480 KB ----------------
#define OFF_GI1   0ull         // [16][768]  gi1(t) staged (same-wg rows)
#define OFF_H1    12288ull     // [16][256]
#define OFF_H2    16384ull     // [16][256]  (state0 initially)
#define OFF_QCS   20480ull     // [2][16][256] ctx part of query (+b_q+b_cov+b_cum), parity by t
#define OFF_QHP   28672ull     // [16][16][256] query h1-partials per wg
#define OFF_CLSP  94208ull     // [16][16][4]
#define OFF_LOG   95232ull     // [16][512]
#define OFF_SAW   103424ull    // [16][513]
#define OFF_CSAW  111632ull    // [16][513]
#define OFF_FLG   119840ull    // [16][16] uint epoch flags
// total 120,096 floats = 480,384 B

__device__ __forceinline__ float tanh_fast(float x){
  float e = __expf(2.f*x);
  return 1.f - 2.f/(e + 1.f);
}
__device__ __forceinline__ float sigm_fast(float x){
  return 1.f/(1.f + __expf(-x));
}

// ---------------- init ----------------
__global__ void init_k(float* __restrict__ ws){
  int tid = threadIdx.x;
  for (int i = tid; i < 16*513; i += 256){
    ws[OFF_SAW + i]  = 0.f;
    ws[OFF_CSAW + i] = 0.f;
  }
  unsigned int* flg = (unsigned int*)(ws + OFF_FLG);
  if (tid < 256) flg[tid] = 0u;
}

// ---------------- state0 = mean-pooled 1x1 conv -> OFF_H2 ----------------
__global__ void state0_k(const float* __restrict__ feats, const float* __restrict__ w_si,
                         const float* __restrict__ b_si, float* __restrict__ ws){
  const int b = blockIdx.x, tid = threadIdx.x;
  __shared__ float S[256];
  const float* row = feats + ((size_t)(b*256 + tid))*512;
  float a0=0.f,a1=0.f,a2=0.f,a3=0.f;
  for (int n=0;n<512;n+=4){ a0+=row[n]; a1+=row[n+1]; a2+=row[n+2]; a3+=row[n+3]; }
  S[tid] = (a0+a1)+(a2+a3);        // BOS column is zeros
  __syncthreads();
  const float* wr = w_si + (size_t)tid*256;
  float acc = 0.f;
  for (int c=0;c<256;c++) acc += wr[c]*S[c];
  ws[OFF_H2 + b*256 + tid] = acc/513.f + b_si[tid];
}

// ---------------- flag barrier: 1 writer + 16 parallel polls per wg ----------------
__device__ __forceinline__ void group_bar(unsigned int* flg, int j, unsigned int ep){
  __threadfence();                 // release my wg's global writes
  __syncthreads();
  if (threadIdx.x == 0)
    __hip_atomic_store(flg + j, ep, __ATOMIC_RELAXED, __HIP_MEMORY_SCOPE_AGENT);
  if (threadIdx.x < 16){
    while (__hip_atomic_load(flg + threadIdx.x, __ATOMIC_RELAXED, __HIP_MEMORY_SCOPE_AGENT) < ep)
      __builtin_amdgcn_s_sleep(1);
  }
  __syncthreads();
  __threadfence();                 // acquire
}

// ---------------- persistent scan kernel ----------------
__global__ __launch_bounds__(256, 1) void persist_k(
    const float* __restrict__ feats,
    const float* __restrict__ w_fp,  const float* __restrict__ b_fp,
    const float* __restrict__ w_ih1, const float* __restrict__ b_ih1,
    const float* __restrict__ w_hh1, const float* __restrict__ b_hh1,
    const float* __restrict__ w_ih2, const float* __restrict__ b_ih2,
    const float* __restrict__ w_hh2, const float* __restrict__ b_hh2,
    const float* __restrict__ w_q,   const float* __restrict__ b_q,
    const float* __restrict__ w_cov, const float* __restrict__ b_cov,
    const float* __restrict__ w_cum, const float* __restrict__ b_cum,
    const float* __restrict__ w_logit, const float* __restrict__ b_logit,
    const float* __restrict__ w_c1,  const float* __restrict__ b_c1,
    const float* __restrict__ w_c2,  const float* __restrict__ b_c2,
    float* __restrict__ ws, float* __restrict__ d_out)
{
  const int tid  = threadIdx.x;
  const int g    = (blockIdx.x & 7)*2 + ((blockIdx.x >> 3) & 1);   // batch (XCD-local group)
  const int j    = blockIdx.x >> 4;                                 // wg in group 0..15
  const int lane = tid & 63;
  const int wv   = tid >> 6;

  float* out_pred = d_out;              // [512][16]
  float* out_att  = d_out + 8192;       // [512][16][512]

  __shared__ __align__(16) float proj_l[32*256];
  __shared__ __align__(16) float fstage[256][9];
  __shared__ float h1s[256], h2s[256];
  __shared__ __align__(16) float query_s[256];
  __shared__ float cbuf[2][256];
  __shared__ float ctxP[256];
  __shared__ float saw_s[40], csaw_s[40];
  __shared__ float gh1_l[48], gh2_l[48], gi2_l[48], h1n_l[16], tanh_l[16];
  __shared__ float logit_s[512];
  __shared__ float redf[256]; __shared__ int redi[256];
  __shared__ float wc2s[4][16]; __shared__ float bc2s[4];

  // ---- per-thread register weights ----
  float wcov[4][7], wcum[4][7], wl[4];
  #pragma unroll
  for (int u=0; u<4; ++u){
    int p = 4*lane + u;
    wl[u] = w_logit[p];
    #pragma unroll
    for (int k=0; k<7; ++k){ wcov[u][k] = w_cov[p*7+k]; wcum[u][k] = w_cum[p*7+k]; }
  }
  const float blog = b_logit[0];

  const int ol = tid >> 2;            // <48: 3 gates x 16 h-rows of this wg's chunk
  const int qq = tid & 3;
  int grow = 0; float bh1=0.f, bh2=0.f, bi1=0.f, bi2=0.f;
  float wh1[64], wih1[64], wh2[64], wih2[64];
  if (ol < 48){
    int gate = ol >> 4, u = ol & 15;
    grow = gate*256 + 16*j + u;
    bh1 = b_hh1[grow]; bh2 = b_hh2[grow];
    bi1 = b_ih1[grow]; bi2 = b_ih2[grow];
    #pragma unroll
    for (int i=0; i<64; ++i){
      wh1[i]  = w_hh1[(size_t)grow*256 + qq + 4*i];
      wih1[i] = w_ih1[(size_t)grow*256 + qq + 4*i];
      wh2[i]  = w_hh2[(size_t)grow*256 + qq + 4*i];
      wih2[i] = w_ih2[(size_t)grow*256 + qq + 4*i];
    }
  } else {
    #pragma unroll
    for (int i=0; i<64; ++i){ wh1[i]=0.f; wih1[i]=0.f; wh2[i]=0.f; wih2[i]=0.f; }
  }
  float wqr[16];
  #pragma unroll
  for (int i=0; i<16; ++i) wqr[i] = w_q[(size_t)tid*512 + 256 + 16*j + i];

  const int c_ol = tid >> 4, c_qp = tid & 15;
  const int prow = 16*j + c_ol;
  float wc1r[16], wcc[16], wcp[16], wqc[16];
  #pragma unroll
  for (int i=0; i<16; ++i){
    wc1r[i] = w_c1[(size_t)prow*768 + 512 + c_qp + 16*i];
    wcc[i]  = w_c1[(size_t)prow*768 +   0 + c_qp + 16*i];
    wcp[i]  = w_c1[(size_t)prow*768 + 256 + c_qp + 16*i];
    wqc[i]  = w_q [(size_t)prow*512 +   0 + c_qp + 16*i];
  }
  const float bcl = b_c1[prow];
  const float bqc = b_q[prow] + b_cov[prow] + b_cum[prow];

  if (tid < 64) wc2s[tid>>4][tid&15] = w_c2[(tid>>4)*256 + 16*j + (tid&15)];
  if (tid < 4)  bc2s[tid] = b_c2[tid];

  // ---- prologue: ctx(0), proj slice, gi1(0), qc(0) ----
  cbuf[0][tid] = feats[(size_t)(g*256 + tid)*512 + 0];
  {
    const float* fr = feats + ((size_t)(g*256 + tid))*512;
    const float* wr = w_fp + (size_t)tid*256;
    const float bfp = b_fp[tid];
    for (int z=0; z<4; ++z){
      for (int cc=0; cc<8; ++cc){
        int pos = 32*j + 8*z + cc;            // fusion position = feats_p col
        fstage[tid][cc] = (pos >= 1) ? fr[pos-1] : 0.f;
      }
      __syncthreads();
      float pacc[8] = {0,0,0,0,0,0,0,0};
      for (int c=0; c<256; ++c){
        float w = wr[c];
        #pragma unroll
        for (int cc=0; cc<8; ++cc) pacc[cc] += w * fstage[c][cc];
      }
      __syncthreads();
      #pragma unroll
      for (int cc=0; cc<8; ++cc) proj_l[(8*z+cc)*256 + tid] = pacc[cc] + bfp;
    }
  }
  __syncthreads();
  if (ol < 48){                               // gi1(0)
    float s = 0.f;
    #pragma unroll
    for (int i=0; i<64; ++i) s += wih1[i]*cbuf[0][qq + 4*i];
    s += __shfl_xor(s, 1, 64); s += __shfl_xor(s, 2, 64);
    if (qq == 0) ws[OFF_GI1 + g*768 + grow] = s + bi1;
  }
  {                                            // qc(0)
    float s = 0.f;
    #pragma unroll
    for (int i=0; i<16; ++i) s += wqc[i]*cbuf[0][c_qp + 16*i];
    s += __shfl_xor(s, 1, 64); s += __shfl_xor(s, 2, 64);
    s += __shfl_xor(s, 4, 64); s += __shfl_xor(s, 8, 64);
    if (c_qp == 0) ws[OFF_QCS + 0*4096 + g*256 + prow] = s + bqc;
  }

  unsigned int* flg = (unsigned int*)(ws + OFF_FLG) + g*16;
  unsigned int ep = 0;
  float cls_ctx = 0.f;

  for (int t = 0; t <= 512; ++t){
    // ================= P0 =================
    h2s[tid] = ws[OFF_H2 + g*256 + tid];
    if (t < 511) cbuf[(t+1)&1][tid] = feats[(size_t)(g*256 + tid)*512 + (t+1)];
    if (t < 512 && tid < 40){
      int r = 32*j - 3 + tid;
      bool ok = (r >= 0 && r < 513);
      saw_s[tid]  = ok ? ws[OFF_SAW  + g*513 + r] : 0.f;
      csaw_s[tid] = ok ? ws[OFF_CSAW + g*513 + r] : 0.f;
    }
    __syncthreads();
    if (t < 512){
      if (ol < 48){                            // gh1(t) over full h2(t-1)
        float s = 0.f;
        #pragma unroll
        for (int i=0; i<64; ++i) s += wh1[i]*h2s[qq + 4*i];
        s += __shfl_xor(s, 1, 64); s += __shfl_xor(s, 2, 64);
        if (qq == 0) gh1_l[ol] = s + bh1;
      }
    }
    if (t >= 1){                               // cls(t-1) partials
      float s = 0.f;
      #pragma unroll
      for (int i=0; i<16; ++i){
        int d = c_qp + 16*i;
        s += wc1r[i]*h2s[d] + wcp[i]*ctxP[d];
      }
      s += __shfl_xor(s, 1, 64); s += __shfl_xor(s, 2, 64);
      s += __shfl_xor(s, 4, 64); s += __shfl_xor(s, 8, 64);
      if (c_qp == 0) tanh_l[c_ol] = tanh_fast(s + cls_ctx + bcl);
    }
    __syncthreads();
    if (t >= 1 && tid < 4){
      float sum = 0.f;
      #pragma unroll
      for (int o=0; o<16; ++o) sum += wc2s[tid][o]*tanh_l[o];
      ws[OFF_CLSP + (g*16 + j)*4 + tid] = sum;
    }
    if (t < 512 && tid < 16){                  // h1(t) own rows
      int ig = 16*j + tid;
      size_t gb = OFF_GI1 + g*768;
      float r  = sigm_fast(ws[gb +       16*j + tid] + gh1_l[tid]);
      float z  = sigm_fast(ws[gb + 256 + 16*j + tid] + gh1_l[16 + tid]);
      float nn = tanh_fast(ws[gb + 512 + 16*j + tid] + r*gh1_l[32 + tid]);
      float h1v = (1.f - z)*nn + z*h2s[ig];
      ws[OFF_H1 + g*256 + ig] = h1v;
      h1n_l[tid] = h1v;
    }
    __syncthreads();
    if (t < 512){                              // query h1-partial
      float s = 0.f;
      #pragma unroll
      for (int i=0; i<16; ++i) s += wqr[i]*h1n_l[i];
      ws[OFF_QHP + (g*16 + j)*256 + tid] = s;
    }
    group_bar(flg, j, ++ep);   // BAR A
    // ================= P1 =================
    if (t < 512){
      h1s[tid] = ws[OFF_H1 + g*256 + tid];
      float q = ws[OFF_QCS + (size_t)(t&1)*4096 + g*256 + tid];
      #pragma unroll
      for (int jj=0; jj<16; ++jj) q += ws[OFF_QHP + (g*16 + jj)*256 + tid];
      query_s[tid] = q;
    }
    __syncthreads();
    if (t < 512){
      float qv[4];
      { float4 q4 = *(const float4*)&query_s[4*lane]; qv[0]=q4.x; qv[1]=q4.y; qv[2]=q4.z; qv[3]=q4.w; }
      #pragma unroll
      for (int i=0; i<8; ++i){
        int ln = 8*wv + i;
        int n  = 32*j + ln;
        float4 pj = *(const float4*)&proj_l[ln*256 + 4*lane];
        float pv[4] = {pj.x, pj.y, pj.z, pj.w};
        float sw[7], cw[7];
        #pragma unroll
        for (int k=0; k<7; ++k){ sw[k] = saw_s[ln+k]; cw[k] = csaw_s[ln+k]; }
        float s = 0.f;
        #pragma unroll
        for (int u=0; u<4; ++u){
          float f = pv[u] + qv[u];
          #pragma unroll
          for (int k=0; k<7; ++k) f += wcov[u][k]*sw[k] + wcum[u][k]*cw[k];
          s += wl[u]*tanh_fast(f);
        }
        #pragma unroll
        for (int mm=32; mm>=1; mm>>=1) s += __shfl_xor(s, mm, 64);
        if (lane == 0){
          float lg = s + blog;
          ws[OFF_LOG + g*512 + n] = lg;
          out_att[((size_t)t*16 + g)*512 + n] = lg;
        }
      }
      if (ol < 48){                            // gh2(t) over full h1(t)
        float s = 0.f;
        #pragma unroll
        for (int i=0; i<64; ++i) s += wh2[i]*h1s[qq + 4*i];
        s += __shfl_xor(s, 1, 64); s += __shfl_xor(s, 2, 64);
        if (qq == 0) gh2_l[ol] = s + bh2;
      }
      if (t < 511){
        const float* cN = cbuf[(t+1)&1];
        if (ol < 48){                          // gi1(t+1)
          float s = 0.f;
          #pragma unroll
          for (int i=0; i<64; ++i) s += wih1[i]*cN[qq + 4*i];
          s += __shfl_xor(s, 1, 64); s += __shfl_xor(s, 2, 64);
          if (qq == 0) ws[OFF_GI1 + g*768 + grow] = s + bi1;
        }
        {                                      // qc(t+1)
          float s = 0.f;
          #pragma unroll
          for (int i=0; i<16; ++i) s += wqc[i]*cN[c_qp + 16*i];
          s += __shfl_xor(s, 1, 64); s += __shfl_xor(s, 2, 64);
          s += __shfl_xor(s, 4, 64); s += __shfl_xor(s, 8, 64);
          if (c_qp == 0) ws[OFF_QCS + (size_t)((t+1)&1)*4096 + g*256 + prow] = s + bqc;
        }
      }
    }
    if (t >= 1 && j == 0 && wv == 0){          // finalize pred(t-1)
      float s = 0.f;
      if (lane < 4){
        s = bc2s[lane];
        #pragma unroll
        for (int jj=0; jj<16; ++jj) s += ws[OFF_CLSP + (g*16 + jj)*4 + lane];
      }
      float v0 = __shfl(s, 0, 64), v1 = __shfl(s, 1, 64);
      float v2 = __shfl(s, 2, 64), v3 = __shfl(s, 3, 64);
      if (lane == 0){
        int pb = 0; float bv = v0;
        if (v1 > bv){ bv = v1; pb = 1; }
        if (v2 > bv){ bv = v2; pb = 2; }
        if (v3 > bv){ bv = v3; pb = 3; }
        out_pred[(t-1)*16 + g] = (float)pb;
      }
    }
    group_bar(flg, j, ++ep);   // BAR B
    // ================= P2 =================
    if (t < 512){
      logit_s[tid]       = ws[OFF_LOG + g*512 + tid];
      logit_s[tid + 256] = ws[OFF_LOG + g*512 + tid + 256];
      __syncthreads();
      float v1 = (tid <= t) ? logit_s[tid] : -3.0e38f; int i1 = tid;
      { float v2 = (tid+256 <= t) ? logit_s[tid+256] : -3.0e38f;
        if (v2 > v1){ v1 = v2; i1 = tid + 256; } }
      redf[tid] = v1; redi[tid] = i1;
      __syncthreads();
      for (int s2=128; s2>=1; s2>>=1){
        if (tid < s2){
          float bv = redf[tid+s2]; int bi = redi[tid+s2];
          if (bv > redf[tid] || (bv == redf[tid] && bi < redi[tid])){ redf[tid]=bv; redi[tid]=bi; }
        }
        __syncthreads();
      }
      float mx = redf[0]; int idx = redi[0];
      __syncthreads();
      float e1 = (tid <= t)     ? __expf(logit_s[tid]     - mx) : 0.f;
      float e2 = (tid+256 <= t) ? __expf(logit_s[tid+256] - mx) : 0.f;
      redf[tid] = e1 + e2;
      __syncthreads();
      for (int s2=128; s2>=1; s2>>=1){
        if (tid < s2) redf[tid] += redf[tid+s2];
        __syncthreads();
      }
      float invZ = 1.f / redf[0];
      if (tid < 32){
        int n = 32*j + tid;
        float a = (n <= t) ? __expf(logit_s[n] - mx)*invZ : 0.f;
        ws[OFF_SAW  + g*513 + n] = a;
        ws[OFF_CSAW + g*513 + n] += a;
      }
      {                                        // cls ctx part for cls(t), carried in register
        const float* cT = cbuf[t&1];
        float s = 0.f;
        #pragma unroll
        for (int i=0; i<16; ++i) s += wcc[i]*cT[c_qp + 16*i];
        s += __shfl_xor(s, 1, 64); s += __shfl_xor(s, 2, 64);
        s += __shfl_xor(s, 4, 64); s += __shfl_xor(s, 8, 64);
        cls_ctx = s;
      }
      ctxP[tid] = (idx >= 1) ? feats[(size_t)(g*256 + tid)*512 + idx - 1] : 0.f;
      __syncthreads();
      if (ol < 48){                            // gi2(t) over parent column
        float s = 0.f;
        #pragma unroll
        for (int i=0; i<64; ++i) s += wih2[i]*ctxP[qq + 4*i];
        s += __shfl_xor(s, 1, 64); s += __shfl_xor(s, 2, 64);
        if (qq == 0) gi2_l[ol] = s + bi2;
      }
      __syncthreads();
      if (tid < 16){                           // h2(t) own rows
        int ig = 16*j + tid;
        float r  = sigm_fast(gi2_l[tid]      + gh2_l[tid]);
        float z  = sigm_fast(gi2_l[16 + tid] + gh2_l[16 + tid]);
        float nn = tanh_fast(gi2_l[32 + tid] + r*gh2_l[32 + tid]);
        ws[OFF_H2 + g*256 + ig] = (1.f - z)*nn + z*h1s[ig];
      }
    }
    group_bar(flg, j, ++ep);   // BAR C
  }
}

extern "C" void kernel_launch(void* const* d_in, const int* in_sizes, int n_in,
                              void* d_out, int out_size, void* d_ws, size_t ws_size,
                              hipStream_t stream)
{
  (void)in_sizes; (void)n_in; (void)out_size; (void)ws_size;
  const float* feats   = (const float*)d_in[0];
  const float* w_fp    = (const float*)d_in[2];
  const float* b_fp    = (const float*)d_in[3];
  const float* w_si    = (const float*)d_in[4];
  const float* b_si    = (const float*)d_in[5];
  const float* w_ih1   = (const float*)d_in[6];
  const float* w_hh1   = (const float*)d_in[7];
  const float* b_ih1   = (const float*)d_in[8];
  const float* b_hh1   = (const float*)d_in[9];
  const float* w_ih2   = (const float*)d_in[10];
  const float* w_hh2   = (const float*)d_in[11];
  const float* b_ih2   = (const float*)d_in[12];
  const float* b_hh2   = (const float*)d_in[13];
  const float* w_q     = (const float*)d_in[14];
  const float* b_q     = (const float*)d_in[15];
  const float* w_cov   = (const float*)d_in[16];
  const float* b_cov   = (const float*)d_in[17];
  const float* w_cum   = (const float*)d_in[18];
  const float* b_cum   = (const float*)d_in[19];
  const float* w_logit = (const float*)d_in[20];
  const float* b_logit = (const float*)d_in[21];
  const float* w_c1    = (const float*)d_in[22];
  const float* b_c1    = (const float*)d_in[23];
  const float* w_c2    = (const float*)d_in[24];
  const float* b_c2    = (const float*)d_in[25];
  float* ws  = (float*)d_ws;
  float* out = (float*)d_out;

  init_k<<<1, 256, 0, stream>>>(ws);
  state0_k<<<16, 256, 0, stream>>>(feats, w_si, b_si, ws);
  persist_k<<<256, 256, 0, stream>>>(feats, w_fp, b_fp, w_ih1, b_ih1,
                                     w_hh1, b_hh1, w_ih2, b_ih2, w_hh2, b_hh2,
                                     w_q, b_q, w_cov, b_cov, w_cum, b_cum,
                                     w_logit, b_logit, w_c1, b_c1, w_c2, b_c2,
                                     ws, out);
}

// Round 6
// 13263.721 us; speedup vs baseline: 4.7273x; 4.7273x over previous
//
#include <hip/hip_runtime.h>

// ---------------- workspace layout (float units), total ~366 KB ----------------
#define OFF_H1    0ull         // [16][256]
#define OFF_H2    4096ull      // [16][256]  (state0 initially)
#define OFF_QCS   8192ull      // [2][16][256] ctx part of query (+b_q+b_cov+b_cum), parity by t
#define OFF_QHP   16384ull     // [16][16][256] query h1-partials per wg
#define OFF_CLSP  81920ull     // [16][16][4]
#define OFF_LOG   82944ull     // [16][512]
#define OFF_FLG   91136ull     // [16][16] uint epoch flags

__device__ __forceinline__ float tanh_fast(float x){
  float e = __expf(2.f*x);
  return 1.f - 2.f/(e + 1.f);
}
__device__ __forceinline__ float sigm_fast(float x){
  return 1.f/(1.f + __expf(-x));
}
// coherent (L2-bypassing, agent-scope) accesses for cross-wg data
__device__ __forceinline__ float ldc(const float* p){
  return __hip_atomic_load((float*)p, __ATOMIC_RELAXED, __HIP_MEMORY_SCOPE_AGENT);
}
__device__ __forceinline__ void stc(float* p, float v){
  __hip_atomic_store(p, v, __ATOMIC_RELAXED, __HIP_MEMORY_SCOPE_AGENT);
}

// ---------------- init: zero barrier flags ----------------
__global__ void init_k(float* __restrict__ ws){
  unsigned int* flg = (unsigned int*)(ws + OFF_FLG);
  if (threadIdx.x < 256) flg[threadIdx.x] = 0u;
}

// ---------------- state0 = mean-pooled 1x1 conv -> OFF_H2 ----------------
__global__ void state0_k(const float* __restrict__ feats, const float* __restrict__ w_si,
                         const float* __restrict__ b_si, float* __restrict__ ws){
  const int b = blockIdx.x, tid = threadIdx.x;
  __shared__ float S[256];
  const float* row = feats + ((size_t)(b*256 + tid))*512;
  float a0=0.f,a1=0.f,a2=0.f,a3=0.f;
  for (int n=0;n<512;n+=4){ a0+=row[n]; a1+=row[n+1]; a2+=row[n+2]; a3+=row[n+3]; }
  S[tid] = (a0+a1)+(a2+a3);        // BOS column is zeros
  __syncthreads();
  const float* wr = w_si + (size_t)tid*256;
  float acc = 0.f;
  for (int c=0;c<256;c++) acc += wr[c]*S[c];
  ws[OFF_H2 + b*256 + tid] = acc/513.f + b_si[tid];
}

// ---------------- fence-free flag barrier ----------------
// All shared data moves via sc1 (agent-scope relaxed) atomics which bypass the
// per-XCD L2, so no buffer_wbl2/buffer_inv is needed. s_waitcnt(0) drains each
// wave's outstanding stores before the wg signals.
__device__ __forceinline__ void group_bar(unsigned int* flg, int j, unsigned int ep){
  __builtin_amdgcn_s_waitcnt(0);   // vmcnt=0 lgkmcnt=0: my stores reached coherence point
  __syncthreads();                 // all waves of this wg drained
  if (threadIdx.x == 0)
    __hip_atomic_store(flg + j, ep, __ATOMIC_RELAXED, __HIP_MEMORY_SCOPE_AGENT);
  if (threadIdx.x < 16){
    while (__hip_atomic_load(flg + threadIdx.x, __ATOMIC_RELAXED, __HIP_MEMORY_SCOPE_AGENT) < ep)
      __builtin_amdgcn_s_sleep(1);
  }
  __syncthreads();
}

// ---------------- persistent scan kernel ----------------
__global__ __launch_bounds__(256, 1) void persist_k(
    const float* __restrict__ feats,
    const float* __restrict__ w_fp,  const float* __restrict__ b_fp,
    const float* __restrict__ w_ih1, const float* __restrict__ b_ih1,
    const float* __restrict__ w_hh1, const float* __restrict__ b_hh1,
    const float* __restrict__ w_ih2, const float* __restrict__ b_ih2,
    const float* __restrict__ w_hh2, const float* __restrict__ b_hh2,
    const float* __restrict__ w_q,   const float* __restrict__ b_q,
    const float* __restrict__ w_cov, const float* __restrict__ b_cov,
    const float* __restrict__ w_cum, const float* __restrict__ b_cum,
    const float* __restrict__ w_logit, const float* __restrict__ b_logit,
    const float* __restrict__ w_c1,  const float* __restrict__ b_c1,
    const float* __restrict__ w_c2,  const float* __restrict__ b_c2,
    float* __restrict__ ws, float* __restrict__ d_out)
{
  const int tid  = threadIdx.x;
  const int g    = (blockIdx.x & 7)*2 + ((blockIdx.x >> 3) & 1);   // batch (XCD-local group)
  const int j    = blockIdx.x >> 4;                                 // wg in group 0..15
  const int lane = tid & 63;
  const int wv   = tid >> 6;

  float* out_pred = d_out;              // [512][16]
  float* out_att  = d_out + 8192;       // [512][16][512]

  __shared__ __align__(16) float proj_l[32*256];
  __shared__ __align__(16) float fstage[256][9];
  __shared__ float h1s[256], h2s[256];
  __shared__ __align__(16) float query_s[256];
  __shared__ float cbuf[2][256];
  __shared__ float ctxP[256];
  __shared__ float saw_s[40], csaw_s[40];    // per-wg window, LDS-persistent
  __shared__ float gh1_l[48], gh2_l[48], gi2_l[48], gi1_s[48], h1n_l[16], tanh_l[16];
  __shared__ float logit_s[512];
  __shared__ float redf[256]; __shared__ int redi[256];
  __shared__ float wc2s[4][16]; __shared__ float bc2s[4];

  // ---- per-thread register weights ----
  float wcov[4][7], wcum[4][7], wl[4];
  #pragma unroll
  for (int u=0; u<4; ++u){
    int p = 4*lane + u;
    wl[u] = w_logit[p];
    #pragma unroll
    for (int k=0; k<7; ++k){ wcov[u][k] = w_cov[p*7+k]; wcum[u][k] = w_cum[p*7+k]; }
  }
  const float blog = b_logit[0];

  const int ol = tid >> 2;            // <48: 3 gates x 16 h-rows of this wg's chunk
  const int qq = tid & 3;
  int grow = 0; float bh1=0.f, bh2=0.f, bi1=0.f, bi2=0.f;
  float wh1[64], wih1[64], wh2[64], wih2[64];
  if (ol < 48){
    int gate = ol >> 4, u = ol & 15;
    grow = gate*256 + 16*j + u;
    bh1 = b_hh1[grow]; bh2 = b_hh2[grow];
    bi1 = b_ih1[grow]; bi2 = b_ih2[grow];
    #pragma unroll
    for (int i=0; i<64; ++i){
      wh1[i]  = w_hh1[(size_t)grow*256 + qq + 4*i];
      wih1[i] = w_ih1[(size_t)grow*256 + qq + 4*i];
      wh2[i]  = w_hh2[(size_t)grow*256 + qq + 4*i];
      wih2[i] = w_ih2[(size_t)grow*256 + qq + 4*i];
    }
  } else {
    #pragma unroll
    for (int i=0; i<64; ++i){ wh1[i]=0.f; wih1[i]=0.f; wh2[i]=0.f; wih2[i]=0.f; }
  }
  float wqr[16];
  #pragma unroll
  for (int i=0; i<16; ++i) wqr[i] = w_q[(size_t)tid*512 + 256 + 16*j + i];

  const int c_ol = tid >> 4, c_qp = tid & 15;
  const int prow = 16*j + c_ol;
  float wc1r[16], wcc[16], wcp[16], wqc[16];
  #pragma unroll
  for (int i=0; i<16; ++i){
    wc1r[i] = w_c1[(size_t)prow*768 + 512 + c_qp + 16*i];
    wcc[i]  = w_c1[(size_t)prow*768 +   0 + c_qp + 16*i];
    wcp[i]  = w_c1[(size_t)prow*768 + 256 + c_qp + 16*i];
    wqc[i]  = w_q [(size_t)prow*512 +   0 + c_qp + 16*i];
  }
  const float bcl = b_c1[prow];
  const float bqc = b_q[prow] + b_cov[prow] + b_cum[prow];

  if (tid < 64) wc2s[tid>>4][tid&15] = w_c2[(tid>>4)*256 + 16*j + (tid&15)];
  if (tid < 4)  bc2s[tid] = b_c2[tid];
  if (tid < 40){ saw_s[tid] = 0.f; csaw_s[tid] = 0.f; }

  // ---- prologue: ctx(0), proj slice, gi1(0), qc(0) ----
  cbuf[0][tid] = feats[(size_t)(g*256 + tid)*512 + 0];
  {
    const float* fr = feats + ((size_t)(g*256 + tid))*512;
    const float* wr = w_fp + (size_t)tid*256;
    const float bfp = b_fp[tid];
    for (int z=0; z<4; ++z){
      for (int cc=0; cc<8; ++cc){
        int pos = 32*j + 8*z + cc;            // fusion position = feats_p col
        fstage[tid][cc] = (pos >= 1) ? fr[pos-1] : 0.f;
      }
      __syncthreads();
      float pacc[8] = {0,0,0,0,0,0,0,0};
      for (int c=0; c<256; ++c){
        float w = wr[c];
        #pragma unroll
        for (int cc=0; cc<8; ++cc) pacc[cc] += w * fstage[c][cc];
      }
      __syncthreads();
      #pragma unroll
      for (int cc=0; cc<8; ++cc) proj_l[(8*z+cc)*256 + tid] = pacc[cc] + bfp;
    }
  }
  __syncthreads();
  if (ol < 48){                               // gi1(0) -> LDS (same-wg consumer)
    float s = 0.f;
    #pragma unroll
    for (int i=0; i<64; ++i) s += wih1[i]*cbuf[0][qq + 4*i];
    s += __shfl_xor(s, 1, 64); s += __shfl_xor(s, 2, 64);
    if (qq == 0) gi1_s[ol] = s + bi1;
  }
  {                                            // qc(0)
    float s = 0.f;
    #pragma unroll
    for (int i=0; i<16; ++i) s += wqc[i]*cbuf[0][c_qp + 16*i];
    s += __shfl_xor(s, 1, 64); s += __shfl_xor(s, 2, 64);
    s += __shfl_xor(s, 4, 64); s += __shfl_xor(s, 8, 64);
    if (c_qp == 0) stc(ws + OFF_QCS + 0*4096 + g*256 + prow, s + bqc);
  }
  __syncthreads();

  unsigned int* flg = (unsigned int*)(ws + OFF_FLG) + g*16;
  unsigned int ep = 0;
  float cls_ctx = 0.f;

  for (int t = 0; t <= 512; ++t){
    // ================= P0 =================
    h2s[tid] = ldc(ws + OFF_H2 + g*256 + tid);
    if (t < 511) cbuf[(t+1)&1][tid] = feats[(size_t)(g*256 + tid)*512 + (t+1)];
    __syncthreads();
    if (t < 512){
      if (ol < 48){                            // gh1(t) over full h2(t-1)
        float s = 0.f;
        #pragma unroll
        for (int i=0; i<64; ++i) s += wh1[i]*h2s[qq + 4*i];
        s += __shfl_xor(s, 1, 64); s += __shfl_xor(s, 2, 64);
        if (qq == 0) gh1_l[ol] = s + bh1;
      }
    }
    if (t >= 1){                               // cls(t-1) partials
      float s = 0.f;
      #pragma unroll
      for (int i=0; i<16; ++i){
        int d = c_qp + 16*i;
        s += wc1r[i]*h2s[d] + wcp[i]*ctxP[d];
      }
      s += __shfl_xor(s, 1, 64); s += __shfl_xor(s, 2, 64);
      s += __shfl_xor(s, 4, 64); s += __shfl_xor(s, 8, 64);
      if (c_qp == 0) tanh_l[c_ol] = tanh_fast(s + cls_ctx + bcl);
    }
    __syncthreads();
    if (t >= 1 && tid < 4){
      float sum = 0.f;
      #pragma unroll
      for (int o=0; o<16; ++o) sum += wc2s[tid][o]*tanh_l[o];
      stc(ws + OFF_CLSP + (g*16 + j)*4 + tid, sum);
    }
    if (t < 512 && tid < 16){                  // h1(t) own rows
      int ig = 16*j + tid;
      float r  = sigm_fast(gi1_s[tid]      + gh1_l[tid]);
      float z  = sigm_fast(gi1_s[16 + tid] + gh1_l[16 + tid]);
      float nn = tanh_fast(gi1_s[32 + tid] + r*gh1_l[32 + tid]);
      float h1v = (1.f - z)*nn + z*h2s[ig];
      stc(ws + OFF_H1 + g*256 + ig, h1v);
      h1n_l[tid] = h1v;
    }
    __syncthreads();
    if (t < 512){                              // query h1-partial
      float s = 0.f;
      #pragma unroll
      for (int i=0; i<16; ++i) s += wqr[i]*h1n_l[i];
      stc(ws + OFF_QHP + (g*16 + j)*256 + tid, s);
    }
    group_bar(flg, j, ++ep);   // BAR A
    // ================= P1 =================
    if (t < 512){
      h1s[tid] = ldc(ws + OFF_H1 + g*256 + tid);
      float q = ldc(ws + OFF_QCS + (size_t)(t&1)*4096 + g*256 + tid);
      #pragma unroll
      for (int jj=0; jj<16; ++jj) q += ldc(ws + OFF_QHP + (g*16 + jj)*256 + tid);
      query_s[tid] = q;
    }
    __syncthreads();
    if (t < 512){
      float qv[4];
      { float4 q4 = *(const float4*)&query_s[4*lane]; qv[0]=q4.x; qv[1]=q4.y; qv[2]=q4.z; qv[3]=q4.w; }
      #pragma unroll
      for (int i=0; i<8; ++i){
        int ln = 8*wv + i;
        int n  = 32*j + ln;
        float4 pj = *(const float4*)&proj_l[ln*256 + 4*lane];
        float pv[4] = {pj.x, pj.y, pj.z, pj.w};
        float sw[7], cw[7];
        #pragma unroll
        for (int k=0; k<7; ++k){ sw[k] = saw_s[ln+k]; cw[k] = csaw_s[ln+k]; }
        float s = 0.f;
        #pragma unroll
        for (int u=0; u<4; ++u){
          float f = pv[u] + qv[u];
          #pragma unroll
          for (int k=0; k<7; ++k) f += wcov[u][k]*sw[k] + wcum[u][k]*cw[k];
          s += wl[u]*tanh_fast(f);
        }
        #pragma unroll
        for (int mm=32; mm>=1; mm>>=1) s += __shfl_xor(s, mm, 64);
        if (lane == 0){
          float lg = s + blog;
          stc(ws + OFF_LOG + g*512 + n, lg);
          out_att[((size_t)t*16 + g)*512 + n] = lg;
        }
      }
      if (ol < 48){                            // gh2(t) over full h1(t)
        float s = 0.f;
        #pragma unroll
        for (int i=0; i<64; ++i) s += wh2[i]*h1s[qq + 4*i];
        s += __shfl_xor(s, 1, 64); s += __shfl_xor(s, 2, 64);
        if (qq == 0) gh2_l[ol] = s + bh2;
      }
      if (t < 511){
        const float* cN = cbuf[(t+1)&1];
        if (ol < 48){                          // gi1(t+1) -> LDS
          float s = 0.f;
          #pragma unroll
          for (int i=0; i<64; ++i) s += wih1[i]*cN[qq + 4*i];
          s += __shfl_xor(s, 1, 64); s += __shfl_xor(s, 2, 64);
          if (qq == 0) gi1_s[ol] = s + bi1;
        }
        {                                      // qc(t+1)
          float s = 0.f;
          #pragma unroll
          for (int i=0; i<16; ++i) s += wqc[i]*cN[c_qp + 16*i];
          s += __shfl_xor(s, 1, 64); s += __shfl_xor(s, 2, 64);
          s += __shfl_xor(s, 4, 64); s += __shfl_xor(s, 8, 64);
          if (c_qp == 0) stc(ws + OFF_QCS + (size_t)((t+1)&1)*4096 + g*256 + prow, s + bqc);
        }
      }
    }
    if (t >= 1 && j == 0 && wv == 0){          // finalize pred(t-1)
      float s = 0.f;
      if (lane < 4){
        s = bc2s[lane];
        #pragma unroll
        for (int jj=0; jj<16; ++jj) s += ldc(ws + OFF_CLSP + (g*16 + jj)*4 + lane);
      }
      float v0 = __shfl(s, 0, 64), v1 = __shfl(s, 1, 64);
      float v2 = __shfl(s, 2, 64), v3 = __shfl(s, 3, 64);
      if (lane == 0){
        int pb = 0; float bv = v0;
        if (v1 > bv){ bv = v1; pb = 1; }
        if (v2 > bv){ bv = v2; pb = 2; }
        if (v3 > bv){ bv = v3; pb = 3; }
        out_pred[(t-1)*16 + g] = (float)pb;
      }
    }
    group_bar(flg, j, ++ep);   // BAR B
    // ================= P2 =================
    if (t < 512){
      logit_s[tid]       = ldc(ws + OFF_LOG + g*512 + tid);
      logit_s[tid + 256] = ldc(ws + OFF_LOG + g*512 + tid + 256);
      __syncthreads();
      float v1 = (tid <= t) ? logit_s[tid] : -3.0e38f; int i1 = tid;
      { float v2 = (tid+256 <= t) ? logit_s[tid+256] : -3.0e38f;
        if (v2 > v1){ v1 = v2; i1 = tid + 256; } }
      redf[tid] = v1; redi[tid] = i1;
      __syncthreads();
      for (int s2=128; s2>=1; s2>>=1){
        if (tid < s2){
          float bv = redf[tid+s2]; int bi = redi[tid+s2];
          if (bv > redf[tid] || (bv == redf[tid] && bi < redi[tid])){ redf[tid]=bv; redi[tid]=bi; }
        }
        __syncthreads();
      }
      float mx = redf[0]; int idx = redi[0];
      __syncthreads();
      float e1 = (tid <= t)     ? __expf(logit_s[tid]     - mx) : 0.f;
      float e2 = (tid+256 <= t) ? __expf(logit_s[tid+256] - mx) : 0.f;
      redf[tid] = e1 + e2;
      __syncthreads();
      for (int s2=128; s2>=1; s2>>=1){
        if (tid < s2) redf[tid] += redf[tid+s2];
        __syncthreads();
      }
      float invZ = 1.f / redf[0];
      __syncthreads();
      if (tid < 40){                           // own saw/csaw window from full logits
        int r = 32*j - 3 + tid;
        float a = 0.f;
        if (r >= 0 && r <= t) a = __expf(logit_s[r] - mx)*invZ;   // r<=t<=511 < 512
        saw_s[tid] = a;
        csaw_s[tid] += a;
      }
      {                                        // cls ctx part for cls(t), carried in register
        const float* cT = cbuf[t&1];
        float s = 0.f;
        #pragma unroll
        for (int i=0; i<16; ++i) s += wcc[i]*cT[c_qp + 16*i];
        s += __shfl_xor(s, 1, 64); s += __shfl_xor(s, 2, 64);
        s += __shfl_xor(s, 4, 64); s += __shfl_xor(s, 8, 64);
        cls_ctx = s;
      }
      ctxP[tid] = (idx >= 1) ? feats[(size_t)(g*256 + tid)*512 + idx - 1] : 0.f;
      __syncthreads();
      if (ol < 48){                            // gi2(t) over parent column
        float s = 0.f;
        #pragma unroll
        for (int i=0; i<64; ++i) s += wih2[i]*ctxP[qq + 4*i];
        s += __shfl_xor(s, 1, 64); s += __shfl_xor(s, 2, 64);
        if (qq == 0) gi2_l[ol] = s + bi2;
      }
      __syncthreads();
      if (tid < 16){                           // h2(t) own rows
        int ig = 16*j + tid;
        float r  = sigm_fast(gi2_l[tid]      + gh2_l[tid]);
        float z  = sigm_fast(gi2_l[16 + tid] + gh2_l[16 + tid]);
        float nn = tanh_fast(gi2_l[32 + tid] + r*gh2_l[32 + tid]);
        stc(ws + OFF_H2 + g*256 + ig, (1.f - z)*nn + z*h1s[ig]);
      }
    }
    group_bar(flg, j, ++ep);   // BAR C
  }
}

extern "C" void kernel_launch(void* const* d_in, const int* in_sizes, int n_in,
                              void* d_out, int out_size, void* d_ws, size_t ws_size,
                              hipStream_t stream)
{
  (void)in_sizes; (void)n_in; (void)out_size; (void)ws_size;
  const float* feats   = (const float*)d_in[0];
  const float* w_fp    = (const float*)d_in[2];
  const float* b_fp    = (const float*)d_in[3];
  const float* w_si    = (const float*)d_in[4];
  const float* b_si    = (const float*)d_in[5];
  const float* w_ih1   = (const float*)d_in[6];
  const float* w_hh1   = (const float*)d_in[7];
  const float* b_ih1   = (const float*)d_in[8];
  const float* b_hh1   = (const float*)d_in[9];
  const float* w_ih2   = (const float*)d_in[10];
  const float* w_hh2   = (const float*)d_in[11];
  const float* b_ih2   = (const float*)d_in[12];
  const float* b_hh2   = (const float*)d_in[13];
  const float* w_q     = (const float*)d_in[14];
  const float* b_q     = (const float*)d_in[15];
  const float* w_cov   = (const float*)d_in[16];
  const float* b_cov   = (const float*)d_in[17];
  const float* w_cum   = (const float*)d_in[18];
  const float* b_cum   = (const float*)d_in[19];
  const float* w_logit = (const float*)d_in[20];
  const float* b_logit = (const float*)d_in[21];
  const float* w_c1    = (const float*)d_in[22];
  const float* b_c1    = (const float*)d_in[23];
  const float* w_c2    = (const float*)d_in[24];
  const float* b_c2    = (const float*)d_in[25];
  float* ws  = (float*)d_ws;
  float* out = (float*)d_out;

  init_k<<<1, 256, 0, stream>>>(ws);
  state0_k<<<16, 256, 0, stream>>>(feats, w_si, b_si, ws);
  persist_k<<<256, 256, 0, stream>>>(feats, w_fp, b_fp, w_ih1, b_ih1,
                                     w_hh1, b_hh1, w_ih2, b_ih2, w_hh2, b_hh2,
                                     w_q, b_q, w_cov, b_cov, w_cum, b_cum,
                                     w_logit, b_logit, w_c1, b_c1, w_c2, b_c2,
                                     ws, out);
}

// Round 7
// 12102.196 us; speedup vs baseline: 5.1810x; 1.0960x over previous
//
#include <hip/hip_runtime.h>

// ---------------- workspace layout (float units), ~368 KB ----------------
#define OFF_H1    0ull         // [16][256]
#define OFF_H2    4096ull      // [16][256]  (state0 initially)
#define OFF_QCS   8192ull      // [2][16][256] ctx part of query (+biases), parity by t
#define OFF_QHPT  16384ull     // [16][256][16] query h1-partials, TRANSPOSED (p-major)
#define OFF_CLSP  81920ull     // [16][16][4]
#define OFF_LOG   82944ull     // [16][512]
#define OFF_FLG   91136ull     // [16][16] u32 epoch flags
#define OFF_PRB   91392ull     // [16][16] u32 sc0 visibility probe
#define OFF_VRD   91648ull     // [16][16] u32 probe verdicts

__device__ __forceinline__ float tanh_fast(float x){
  float e = __expf(2.f*x);
  return 1.f - 2.f/(e + 1.f);
}
__device__ __forceinline__ float sigm_fast(float x){
  return 1.f/(1.f + __expf(-x));
}

// ---- sc0 (XCD-L2 scope) primitives ----
__device__ __forceinline__ unsigned ld_u32_sc0(const unsigned* p){
  unsigned v;
  asm volatile("global_load_dword %0, %1, off sc0\n\ts_waitcnt vmcnt(0)"
               : "=v"(v) : "v"(p) : "memory");
  return v;
}
__device__ __forceinline__ void st_u32_sc0(unsigned* p, unsigned v){
  asm volatile("global_store_dword %0, %1, off sc0" :: "v"(p), "v"(v) : "memory");
}
__device__ __forceinline__ float ld_f_sc0(const float* p){
  float v;
  asm volatile("global_load_dword %0, %1, off sc0\n\ts_waitcnt vmcnt(0)"
               : "=v"(v) : "v"(p) : "memory");
  return v;
}
__device__ __forceinline__ void st_f_sc0(float* p, float v){
  asm volatile("global_store_dword %0, %1, off sc0" :: "v"(p), "v"(v) : "memory");
}
__device__ __forceinline__ void ld4x4_sc0(const float* p, float4& a, float4& b, float4& c, float4& d){
  asm volatile("global_load_dwordx4 %0, %4, off sc0\n\t"
               "global_load_dwordx4 %1, %4, off offset:16 sc0\n\t"
               "global_load_dwordx4 %2, %4, off offset:32 sc0\n\t"
               "global_load_dwordx4 %3, %4, off offset:48 sc0\n\t"
               "s_waitcnt vmcnt(0)"
               : "=v"(a), "=v"(b), "=v"(c), "=v"(d) : "v"(p) : "memory");
}

// ---- dual-mode comm: fast = sc0 (XCD-local), slow = system scope (always correct) ----
__device__ __forceinline__ float ldx(const float* p, bool fast){
  if (fast) return ld_f_sc0(p);
  return __hip_atomic_load((float*)p, __ATOMIC_RELAXED, __HIP_MEMORY_SCOPE_SYSTEM);
}
__device__ __forceinline__ void stx(float* p, float v, bool fast){
  if (fast) st_f_sc0(p, v);
  else __hip_atomic_store(p, v, __ATOMIC_RELAXED, __HIP_MEMORY_SCOPE_SYSTEM);
}

// ---------------- init ----------------
__global__ void init_k(float* __restrict__ ws){
  unsigned* u = (unsigned*)(ws + OFF_FLG);
  for (int i = threadIdx.x; i < 768; i += 256) u[i] = 0u;   // FLG+PRB+VRD contiguous
}

// ---------------- state0 = mean-pooled 1x1 conv -> OFF_H2 ----------------
__global__ void state0_k(const float* __restrict__ feats, const float* __restrict__ w_si,
                         const float* __restrict__ b_si, float* __restrict__ ws){
  const int b = blockIdx.x, tid = threadIdx.x;
  __shared__ float S[256];
  const float* row = feats + ((size_t)(b*256 + tid))*512;
  float a0=0.f,a1=0.f,a2=0.f,a3=0.f;
  for (int n=0;n<512;n+=4){ a0+=row[n]; a1+=row[n+1]; a2+=row[n+2]; a3+=row[n+3]; }
  S[tid] = (a0+a1)+(a2+a3);
  __syncthreads();
  const float* wr = w_si + (size_t)tid*256;
  float acc = 0.f;
  for (int c=0;c<256;c++) acc += wr[c]*S[c];
  ws[OFF_H2 + b*256 + tid] = acc/513.f + b_si[tid];
}

// ---------------- split barrier ----------------
__device__ __forceinline__ void bar_arrive(unsigned* flg, int j, unsigned ep, bool fast){
  __builtin_amdgcn_s_waitcnt(0);   // drain my stores to coherence point
  __syncthreads();                 // whole wg drained
  if (threadIdx.x == 0){
    if (fast) st_u32_sc0(flg + j, ep);
    else __hip_atomic_store(flg + j, ep, __ATOMIC_RELAXED, __HIP_MEMORY_SCOPE_SYSTEM);
  }
}
__device__ __forceinline__ void bar_wait(unsigned* flg, unsigned ep, bool fast){
  if (threadIdx.x < 16){
    if (fast){
      while (ld_u32_sc0(flg + threadIdx.x) < ep) __builtin_amdgcn_s_sleep(1);
    } else {
      while (__hip_atomic_load(flg + threadIdx.x, __ATOMIC_RELAXED, __HIP_MEMORY_SCOPE_SYSTEM) < ep)
        __builtin_amdgcn_s_sleep(1);
    }
  }
  __syncthreads();
}

// ---------------- persistent scan kernel ----------------
__global__ __launch_bounds__(256, 1) void persist_k(
    const float* __restrict__ feats,
    const float* __restrict__ w_fp,  const float* __restrict__ b_fp,
    const float* __restrict__ w_ih1, const float* __restrict__ b_ih1,
    const float* __restrict__ w_hh1, const float* __restrict__ b_hh1,
    const float* __restrict__ w_ih2, const float* __restrict__ b_ih2,
    const float* __restrict__ w_hh2, const float* __restrict__ b_hh2,
    const float* __restrict__ w_q,   const float* __restrict__ b_q,
    const float* __restrict__ w_cov, const float* __restrict__ b_cov,
    const float* __restrict__ w_cum, const float* __restrict__ b_cum,
    const float* __restrict__ w_logit, const float* __restrict__ b_logit,
    const float* __restrict__ w_c1,  const float* __restrict__ b_c1,
    const float* __restrict__ w_c2,  const float* __restrict__ b_c2,
    float* __restrict__ ws, float* __restrict__ d_out)
{
  const int tid  = threadIdx.x;
  const int g    = (blockIdx.x & 7)*2 + ((blockIdx.x >> 3) & 1);   // batch (XCD-local group under RR)
  const int j    = blockIdx.x >> 4;                                 // wg in group 0..15
  const int lane = tid & 63;
  const int wv   = tid >> 6;

  float* out_pred = d_out;              // [512][16]
  float* out_att  = d_out + 8192;       // [512][16][512]

  __shared__ __align__(16) float proj_l[32*256];
  __shared__ __align__(16) float fstage[256][9];
  __shared__ float h1s[256], h2s[256];
  __shared__ __align__(16) float query_s[256];
  __shared__ float cbuf[2][256];
  __shared__ float ctxP[256];
  __shared__ float saw_s[40], csaw_s[40];
  __shared__ float gh1_l[48], gh2_l[48], gi2_l[48], gi1_s[48], h1n_l[16], tanh_l[16];
  __shared__ float logit_s[512];
  __shared__ float wc2s[4][16];
  __shared__ int   modev;

  // ---- per-thread register weights ----
  float wcov[4][7], wcum[4][7], wl[4];
  #pragma unroll
  for (int u=0; u<4; ++u){
    int p = 4*lane + u;
    wl[u] = w_logit[p];
    #pragma unroll
    for (int k=0; k<7; ++k){ wcov[u][k] = w_cov[p*7+k]; wcum[u][k] = w_cum[p*7+k]; }
  }
  const float blog = b_logit[0];
  const float bc20 = b_c2[0], bc21 = b_c2[1], bc22 = b_c2[2], bc23 = b_c2[3];

  const int ol = tid >> 2;            // <48: 3 gates x 16 h-rows of this wg's chunk
  const int qq = tid & 3;
  int grow = 0; float bh1=0.f, bh2=0.f, bi1=0.f, bi2=0.f;
  float wh1[64], wih1[64], wh2[64], wih2[64];
  if (ol < 48){
    int gate = ol >> 4, u = ol & 15;
    grow = gate*256 + 16*j + u;
    bh1 = b_hh1[grow]; bh2 = b_hh2[grow];
    bi1 = b_ih1[grow]; bi2 = b_ih2[grow];
    #pragma unroll
    for (int i=0; i<64; ++i){
      wh1[i]  = w_hh1[(size_t)grow*256 + qq + 4*i];
      wih1[i] = w_ih1[(size_t)grow*256 + qq + 4*i];
      wh2[i]  = w_hh2[(size_t)grow*256 + qq + 4*i];
      wih2[i] = w_ih2[(size_t)grow*256 + qq + 4*i];
    }
  } else {
    #pragma unroll
    for (int i=0; i<64; ++i){ wh1[i]=0.f; wih1[i]=0.f; wh2[i]=0.f; wih2[i]=0.f; }
  }
  float wqr[16];
  #pragma unroll
  for (int i=0; i<16; ++i) wqr[i] = w_q[(size_t)tid*512 + 256 + 16*j + i];

  const int c_ol = tid >> 4, c_qp = tid & 15;
  const int prow = 16*j + c_ol;
  float wc1r[16], wcc[16], wcp[16], wqc[16];
  #pragma unroll
  for (int i=0; i<16; ++i){
    wc1r[i] = w_c1[(size_t)prow*768 + 512 + c_qp + 16*i];
    wcc[i]  = w_c1[(size_t)prow*768 +   0 + c_qp + 16*i];
    wcp[i]  = w_c1[(size_t)prow*768 + 256 + c_qp + 16*i];
    wqc[i]  = w_q [(size_t)prow*512 +   0 + c_qp + 16*i];
  }
  const float bcl = b_c1[prow];
  const float bqc = b_q[prow] + b_cov[prow] + b_cum[prow];

  if (tid < 64) wc2s[tid>>4][tid&15] = w_c2[(tid>>4)*256 + 16*j + (tid&15)];
  if (tid < 40){ saw_s[tid] = 0.f; csaw_s[tid] = 0.f; }

  // ---- sc0 visibility probe -> group-uniform mode ----
  bool fast;
  {
    unsigned* prb = (unsigned*)(ws + OFF_PRB);
    unsigned* vrd = (unsigned*)(ws + OFF_VRD);
    if (tid == 0) st_u32_sc0(prb + g*16 + j, 0xC0FFEEu);
    int ok = 1;
    if (tid < 16){
      ok = 0;
      for (int it = 0; it < 3000; ++it){
        if (ld_u32_sc0(prb + g*16 + tid) == 0xC0FFEEu){ ok = 1; break; }
        __builtin_amdgcn_s_sleep(1);
      }
    }
    unsigned long long bal = __ballot(tid < 16 ? (ok != 0) : true);
    int wgok = ((bal & 0xFFFFull) == 0xFFFFull) ? 1 : 0;
    if (tid == 0)
      __hip_atomic_store(vrd + g*16 + j, 1u + (unsigned)wgok, __ATOMIC_RELAXED, __HIP_MEMORY_SCOPE_SYSTEM);
    if (tid < 16){
      unsigned v;
      while ((v = __hip_atomic_load(vrd + g*16 + tid, __ATOMIC_RELAXED, __HIP_MEMORY_SCOPE_SYSTEM)) == 0u)
        __builtin_amdgcn_s_sleep(1);
      ok = (v == 2u) ? 1 : 0;
    }
    bal = __ballot(tid < 16 ? (ok != 0) : true);
    if (tid == 0) modev = ((bal & 0xFFFFull) == 0xFFFFull) ? 1 : 0;
    __syncthreads();
    fast = (modev != 0);
  }

  // ---- prologue: ctx(0), proj slice, gi1(0), qc(0) ----
  cbuf[0][tid] = feats[(size_t)(g*256 + tid)*512 + 0];
  {
    const float* fr = feats + ((size_t)(g*256 + tid))*512;
    const float* wr = w_fp + (size_t)tid*256;
    const float bfp = b_fp[tid];
    for (int z=0; z<4; ++z){
      for (int cc=0; cc<8; ++cc){
        int pos = 32*j + 8*z + cc;
        fstage[tid][cc] = (pos >= 1) ? fr[pos-1] : 0.f;
      }
      __syncthreads();
      float pacc[8] = {0,0,0,0,0,0,0,0};
      for (int c=0; c<256; ++c){
        float w = wr[c];
        #pragma unroll
        for (int cc=0; cc<8; ++cc) pacc[cc] += w * fstage[c][cc];
      }
      __syncthreads();
      #pragma unroll
      for (int cc=0; cc<8; ++cc) proj_l[(8*z+cc)*256 + tid] = pacc[cc] + bfp;
    }
  }
  __syncthreads();
  if (ol < 48){                               // gi1(0) -> LDS
    float s = 0.f;
    #pragma unroll
    for (int i=0; i<64; ++i) s += wih1[i]*cbuf[0][qq + 4*i];
    s += __shfl_xor(s, 1, 64); s += __shfl_xor(s, 2, 64);
    if (qq == 0) gi1_s[ol] = s + bi1;
  }
  {                                            // qc(0)
    float s = 0.f;
    #pragma unroll
    for (int i=0; i<16; ++i) s += wqc[i]*cbuf[0][c_qp + 16*i];
    s += __shfl_xor(s, 1, 64); s += __shfl_xor(s, 2, 64);
    s += __shfl_xor(s, 4, 64); s += __shfl_xor(s, 8, 64);
    if (c_qp == 0) stx(ws + OFF_QCS + 0*4096 + g*256 + prow, s + bqc, fast);
  }
  __syncthreads();

  unsigned* flg = (unsigned*)(ws + OFF_FLG) + g*16;
  unsigned ep = 0;
  float cls_ctx = 0.f;

  for (int t = 0; t <= 512; ++t){
    // ================= P0 =================
    h2s[tid] = ldx(ws + OFF_H2 + g*256 + tid, fast);
    if (t < 511) cbuf[(t+1)&1][tid] = feats[(size_t)(g*256 + tid)*512 + (t+1)];
    __syncthreads();
    if (t < 512 && ol < 48){                   // gh1(t)
      float s = 0.f;
      #pragma unroll
      for (int i=0; i<64; ++i) s += wh1[i]*h2s[qq + 4*i];
      s += __shfl_xor(s, 1, 64); s += __shfl_xor(s, 2, 64);
      if (qq == 0) gh1_l[ol] = s + bh1;
    }
    if (t >= 1){                               // cls(t-1) tanh rows
      float s = 0.f;
      #pragma unroll
      for (int i=0; i<16; ++i){
        int d = c_qp + 16*i;
        s += wc1r[i]*h2s[d] + wcp[i]*ctxP[d];
      }
      s += __shfl_xor(s, 1, 64); s += __shfl_xor(s, 2, 64);
      s += __shfl_xor(s, 4, 64); s += __shfl_xor(s, 8, 64);
      if (c_qp == 0) tanh_l[c_ol] = tanh_fast(s + cls_ctx + bcl);
    }
    __syncthreads();
    if (t < 512 && tid < 16){                  // h1(t) own rows
      int ig = 16*j + tid;
      float r  = sigm_fast(gi1_s[tid]      + gh1_l[tid]);
      float z  = sigm_fast(gi1_s[16 + tid] + gh1_l[16 + tid]);
      float nn = tanh_fast(gi1_s[32 + tid] + r*gh1_l[32 + tid]);
      float h1v = (1.f - z)*nn + z*h2s[ig];
      stx(ws + OFF_H1 + g*256 + ig, h1v, fast);
      h1n_l[tid] = h1v;
    }
    if (t >= 1 && tid < 4){                    // cls partial out
      float sum = 0.f;
      #pragma unroll
      for (int o=0; o<16; ++o) sum += wc2s[tid][o]*tanh_l[o];
      stx(ws + OFF_CLSP + (g*16 + j)*4 + tid, sum, fast);
    }
    __syncthreads();
    if (t < 512){                              // qh partial (transposed layout)
      float s = 0.f;
      #pragma unroll
      for (int i=0; i<16; ++i) s += wqr[i]*h1n_l[i];
      stx(ws + OFF_QHPT + (size_t)g*4096 + tid*16 + j, s, fast);
    }
    bar_arrive(flg, j, ++ep, fast);            // BAR A arrive
    if (t < 511){                              // window: gi1(t+1), qc(t+1)
      const float* cN = cbuf[(t+1)&1];
      if (ol < 48){
        float s = 0.f;
        #pragma unroll
        for (int i=0; i<64; ++i) s += wih1[i]*cN[qq + 4*i];
        s += __shfl_xor(s, 1, 64); s += __shfl_xor(s, 2, 64);
        if (qq == 0) gi1_s[ol] = s + bi1;
      }
      {
        float s = 0.f;
        #pragma unroll
        for (int i=0; i<16; ++i) s += wqc[i]*cN[c_qp + 16*i];
        s += __shfl_xor(s, 1, 64); s += __shfl_xor(s, 2, 64);
        s += __shfl_xor(s, 4, 64); s += __shfl_xor(s, 8, 64);
        if (c_qp == 0) stx(ws + OFF_QCS + (size_t)((t+1)&1)*4096 + g*256 + prow, s + bqc, fast);
      }
    }
    bar_wait(flg, ep, fast);                   // BAR A wait
    // ================= P1 =================
    float lgv[8];
    if (t < 512){
      h1s[tid] = ldx(ws + OFF_H1 + g*256 + tid, fast);
      float q = ldx(ws + OFF_QCS + (size_t)(t&1)*4096 + g*256 + tid, fast);
      const float* qp = ws + OFF_QHPT + (size_t)g*4096 + tid*16;
      if (fast){
        float4 a,b,c,d;
        ld4x4_sc0(qp, a, b, c, d);
        q += (a.x+a.y+a.z+a.w) + (b.x+b.y+b.z+b.w) + (c.x+c.y+c.z+c.w) + (d.x+d.y+d.z+d.w);
      } else {
        #pragma unroll
        for (int jj=0; jj<16; ++jj)
          q += __hip_atomic_load((float*)(qp+jj), __ATOMIC_RELAXED, __HIP_MEMORY_SCOPE_SYSTEM);
      }
      query_s[tid] = q;
    }
    __syncthreads();
    if (t < 512){
      float qv[4];
      { float4 q4 = *(const float4*)&query_s[4*lane]; qv[0]=q4.x; qv[1]=q4.y; qv[2]=q4.z; qv[3]=q4.w; }
      #pragma unroll
      for (int i=0; i<8; ++i){
        int ln = 8*wv + i;
        int n  = 32*j + ln;
        float4 pj = *(const float4*)&proj_l[ln*256 + 4*lane];
        float pv[4] = {pj.x, pj.y, pj.z, pj.w};
        float sw[7], cw[7];
        #pragma unroll
        for (int k=0; k<7; ++k){ sw[k] = saw_s[ln+k]; cw[k] = csaw_s[ln+k]; }
        float s = 0.f;
        #pragma unroll
        for (int u=0; u<4; ++u){
          float f = pv[u] + qv[u];
          #pragma unroll
          for (int k=0; k<7; ++k) f += wcov[u][k]*sw[k] + wcum[u][k]*cw[k];
          s += wl[u]*tanh_fast(f);
        }
        #pragma unroll
        for (int mm=32; mm>=1; mm>>=1) s += __shfl_xor(s, mm, 64);
        float lg = s + blog;
        lgv[i] = lg;
        if (lane == 0) stx(ws + OFF_LOG + g*512 + n, lg, fast);
      }
      if (ol < 48){                            // gh2(t)
        float s = 0.f;
        #pragma unroll
        for (int i=0; i<64; ++i) s += wh2[i]*h1s[qq + 4*i];
        s += __shfl_xor(s, 1, 64); s += __shfl_xor(s, 2, 64);
        if (qq == 0) gh2_l[ol] = s + bh2;
      }
    }
    bar_arrive(flg, j, ++ep, fast);            // BAR B arrive
    if (t < 512 && lane == 0){                 // window: out_att
      #pragma unroll
      for (int i=0; i<8; ++i)
        out_att[((size_t)t*16 + g)*512 + 32*j + 8*wv + i] = lgv[i];
    }
    if (t >= 1 && j == 0 && wv == 0){          // window: pred(t-1) finalize
      float v = ldx(ws + OFF_CLSP + g*64 + lane, fast);
      #pragma unroll
      for (int d2=4; d2<64; d2<<=1) v += __shfl_xor(v, d2, 64);
      float v0 = __shfl(v, 0, 64), v1 = __shfl(v, 1, 64);
      float v2 = __shfl(v, 2, 64), v3 = __shfl(v, 3, 64);
      if (lane == 0){
        v0 += bc20; v1 += bc21; v2 += bc22; v3 += bc23;
        int pb = 0; float bv = v0;
        if (v1 > bv){ bv = v1; pb = 1; }
        if (v2 > bv){ bv = v2; pb = 2; }
        if (v3 > bv){ bv = v3; pb = 3; }
        out_pred[(t-1)*16 + g] = (float)pb;
      }
    }
    bar_wait(flg, ep, fast);                   // BAR B wait
    // ================= P2 =================
    if (t < 512){
      logit_s[tid]       = ldx(ws + OFF_LOG + g*512 + tid, fast);
      logit_s[tid + 256] = ldx(ws + OFF_LOG + g*512 + tid + 256, fast);
      __syncthreads();
      // wave-redundant masked softmax/argmax over n<=t
      float mx; int idx; float invZ;
      {
        float m = -3.0e38f; int mi = 0;
        #pragma unroll
        for (int k=0; k<8; ++k){
          int n = lane + 64*k;
          float vv = (n <= t) ? logit_s[n] : -3.0e38f;
          if (vv > m){ m = vv; mi = n; }
        }
        #pragma unroll
        for (int d2=1; d2<64; d2<<=1){
          float om = __shfl_xor(m, d2, 64); int oi = __shfl_xor(mi, d2, 64);
          if (om > m || (om == m && oi < mi)){ m = om; mi = oi; }
        }
        float z = 0.f;
        #pragma unroll
        for (int k=0; k<8; ++k){
          int n = lane + 64*k;
          if (n <= t) z += __expf(logit_s[n] - m);
        }
        #pragma unroll
        for (int d2=1; d2<64; d2<<=1) z += __shfl_xor(z, d2, 64);
        mx = m; idx = mi; invZ = 1.f/z;
      }
      if (tid < 40){                           // own saw/csaw window (wave 0)
        int r = 32*j - 3 + tid;
        float a = 0.f;
        if (r >= 0 && r <= t) a = __expf(logit_s[r] - mx)*invZ;
        saw_s[tid] = a;
        csaw_s[tid] += a;
      }
      ctxP[tid] = (idx >= 1) ? feats[(size_t)(g*256 + tid)*512 + idx - 1] : 0.f;
      __syncthreads();
      if (ol < 48){                            // gi2(t)
        float s = 0.f;
        #pragma unroll
        for (int i=0; i<64; ++i) s += wih2[i]*ctxP[qq + 4*i];
        s += __shfl_xor(s, 1, 64); s += __shfl_xor(s, 2, 64);
        if (qq == 0) gi2_l[ol] = s + bi2;
      }
      __syncthreads();
      if (tid < 16){                           // h2(t) own rows
        int ig = 16*j + tid;
        float r  = sigm_fast(gi2_l[tid]      + gh2_l[tid]);
        float z  = sigm_fast(gi2_l[16 + tid] + gh2_l[16 + tid]);
        float nn = tanh_fast(gi2_l[32 + tid] + r*gh2_l[32 + tid]);
        stx(ws + OFF_H2 + g*256 + ig, (1.f - z)*nn + z*h1s[ig], fast);
      }
    }
    bar_arrive(flg, j, ++ep, fast);            // BAR C arrive
    if (t < 512){                              // window: cls ctx part for cls(t)
      const float* cT = cbuf[t&1];
      float s = 0.f;
      #pragma unroll
      for (int i=0; i<16; ++i) s += wcc[i]*cT[c_qp + 16*i];
      s += __shfl_xor(s, 1, 64); s += __shfl_xor(s, 2, 64);
      s += __shfl_xor(s, 4, 64); s += __shfl_xor(s, 8, 64);
      cls_ctx = s;
    }
    bar_wait(flg, ep, fast);                   // BAR C wait
  }
}

extern "C" void kernel_launch(void* const* d_in, const int* in_sizes, int n_in,
                              void* d_out, int out_size, void* d_ws, size_t ws_size,
                              hipStream_t stream)
{
  (void)in_sizes; (void)n_in; (void)out_size; (void)ws_size;
  const float* feats   = (const float*)d_in[0];
  const float* w_fp    = (const float*)d_in[2];
  const float* b_fp    = (const float*)d_in[3];
  const float* w_si    = (const float*)d_in[4];
  const float* b_si    = (const float*)d_in[5];
  const float* w_ih1   = (const float*)d_in[6];
  const float* w_hh1   = (const float*)d_in[7];
  const float* b_ih1   = (const float*)d_in[8];
  const float* b_hh1   = (const float*)d_in[9];
  const float* w_ih2   = (const float*)d_in[10];
  const float* w_hh2   = (const float*)d_in[11];
  const float* b_ih2   = (const float*)d_in[12];
  const float* b_hh2   = (const float*)d_in[13];
  const float* w_q     = (const float*)d_in[14];
  const float* b_q     = (const float*)d_in[15];
  const float* w_cov   = (const float*)d_in[16];
  const float* b_cov   = (const float*)d_in[17];
  const float* w_cum   = (const float*)d_in[18];
  const float* b_cum   = (const float*)d_in[19];
  const float* w_logit = (const float*)d_in[20];
  const float* b_logit = (const float*)d_in[21];
  const float* w_c1    = (const float*)d_in[22];
  const float* b_c1    = (const float*)d_in[23];
  const float* w_c2    = (const float*)d_in[24];
  const float* b_c2    = (const float*)d_in[25];
  float* ws  = (float*)d_ws;
  float* out = (float*)d_out;

  init_k<<<1, 256, 0, stream>>>(ws);
  state0_k<<<16, 256, 0, stream>>>(feats, w_si, b_si, ws);
  persist_k<<<256, 256, 0, stream>>>(feats, w_fp, b_fp, w_ih1, b_ih1,
                                     w_hh1, b_hh1, w_ih2, b_ih2, w_hh2, b_hh2,
                                     w_q, b_q, w_cov, b_cov, w_cum, b_cum,
                                     w_logit, b_logit, w_c1, b_c1, w_c2, b_c2,
                                     ws, out);
}

// Round 8
// 11959.216 us; speedup vs baseline: 5.2429x; 1.0120x over previous
//
#include <hip/hip_runtime.h>

// ---------------- workspace layout (float units), ~370 KB ----------------
#define OFF_H1    0ull         // [16][256]
#define OFF_H2    4096ull      // [16][256]  (state0 initially)
#define OFF_QCS   8192ull      // [2][16][256] ctx part of query (+biases), parity by t
#define OFF_QHPT  16384ull     // [16][256][16] query h1-partials, TRANSPOSED (p-major)
#define OFF_CLSP  81920ull     // [16][16][4]
#define OFF_LOG   82944ull     // [16][512]
#define OFF_FLG   91136ull     // [16][16] u32 epoch flags
#define OFF_PRB   91392ull     // [16][16] u32 visibility probe
#define OFF_VRD   91648ull     // [16][16] u32 probe verdicts
#define OFF_TBL   91904ull     // [256] i32 block->xcd table
#define OFF_CNT2  92160ull     // [16] u32 registration counter

__device__ __forceinline__ float tanh_fast(float x){
  float e = __expf(2.f*x);
  return 1.f - 2.f/(e + 1.f);
}
__device__ __forceinline__ float sigm_fast(float x){
  return 1.f/(1.f + __expf(-x));
}

// ---- sc0 loads (bypass L1, read own-XCD L2) ----
__device__ __forceinline__ unsigned ld_u32_sc0(const unsigned* p){
  unsigned v;
  asm volatile("global_load_dword %0, %1, off sc0\n\ts_waitcnt vmcnt(0)"
               : "=v"(v) : "v"(p) : "memory");
  return v;
}
__device__ __forceinline__ float ld_f_sc0(const float* p){
  float v;
  asm volatile("global_load_dword %0, %1, off sc0\n\ts_waitcnt vmcnt(0)"
               : "=v"(v) : "v"(p) : "memory");
  return v;
}
__device__ __forceinline__ void ld4x4_sc0(const float* p, float4& a, float4& b, float4& c, float4& d){
  asm volatile("global_load_dwordx4 %0, %4, off sc0\n\t"
               "global_load_dwordx4 %1, %4, off offset:16 sc0\n\t"
               "global_load_dwordx4 %2, %4, off offset:32 sc0\n\t"
               "global_load_dwordx4 %3, %4, off offset:48 sc0\n\t"
               "s_waitcnt vmcnt(0)"
               : "=v"(a), "=v"(b), "=v"(c), "=v"(d) : "v"(p) : "memory");
}
__device__ __forceinline__ void store_fence(){
  asm volatile("s_waitcnt vmcnt(0) lgkmcnt(0)" ::: "memory");
}

// ---- dual-mode comm: fast = plain store (write-through L1 -> own L2) + sc0 load;
//      slow = system scope (coherence point, always correct) ----
__device__ __forceinline__ float ldx(const float* p, bool fast){
  if (fast) return ld_f_sc0(p);
  return __hip_atomic_load((float*)p, __ATOMIC_RELAXED, __HIP_MEMORY_SCOPE_SYSTEM);
}
__device__ __forceinline__ void stx(float* p, float v, bool fast){
  if (fast) *p = v;
  else __hip_atomic_store(p, v, __ATOMIC_RELAXED, __HIP_MEMORY_SCOPE_SYSTEM);
}

// ---------------- init ----------------
__global__ void init_k(float* __restrict__ ws){
  unsigned* u = (unsigned*)(ws + OFF_FLG);
  for (int i = threadIdx.x; i < 1040; i += 256) u[i] = 0u;  // FLG+PRB+VRD+TBL+CNT2
}

// ---------------- state0 = mean-pooled 1x1 conv -> OFF_H2 ----------------
__global__ void state0_k(const float* __restrict__ feats, const float* __restrict__ w_si,
                         const float* __restrict__ b_si, float* __restrict__ ws){
  const int b = blockIdx.x, tid = threadIdx.x;
  __shared__ float S[256];
  const float* row = feats + ((size_t)(b*256 + tid))*512;
  float a0=0.f,a1=0.f,a2=0.f,a3=0.f;
  for (int n=0;n<512;n+=4){ a0+=row[n]; a1+=row[n+1]; a2+=row[n+2]; a3+=row[n+3]; }
  S[tid] = (a0+a1)+(a2+a3);
  __syncthreads();
  const float* wr = w_si + (size_t)tid*256;
  float acc = 0.f;
  for (int c=0;c<256;c++) acc += wr[c]*S[c];
  ws[OFF_H2 + b*256 + tid] = acc/513.f + b_si[tid];
}

// ---------------- split barrier ----------------
__device__ __forceinline__ void bar_arrive(unsigned* flg, int j, unsigned ep, bool fast){
  store_fence();                   // drain my stores to (at least) own L2
  __syncthreads();                 // whole wg drained
  if (threadIdx.x == 0){
    if (fast) flg[j] = ep;
    else __hip_atomic_store(flg + j, ep, __ATOMIC_RELAXED, __HIP_MEMORY_SCOPE_SYSTEM);
  }
}
__device__ __forceinline__ void bar_wait(unsigned* flg, unsigned ep, bool fast){
  if (threadIdx.x < 16){
    if (fast){
      while (ld_u32_sc0(flg + threadIdx.x) < ep) __builtin_amdgcn_s_sleep(1);
    } else {
      while (__hip_atomic_load(flg + threadIdx.x, __ATOMIC_RELAXED, __HIP_MEMORY_SCOPE_SYSTEM) < ep)
        __builtin_amdgcn_s_sleep(1);
    }
  }
  __syncthreads();
}

// ---------------- persistent scan kernel ----------------
__global__ __launch_bounds__(256, 1) void persist_k(
    const float* __restrict__ feats,
    const float* __restrict__ w_fp,  const float* __restrict__ b_fp,
    const float* __restrict__ w_ih1, const float* __restrict__ b_ih1,
    const float* __restrict__ w_hh1, const float* __restrict__ b_hh1,
    const float* __restrict__ w_ih2, const float* __restrict__ b_ih2,
    const float* __restrict__ w_hh2, const float* __restrict__ b_hh2,
    const float* __restrict__ w_q,   const float* __restrict__ b_q,
    const float* __restrict__ w_cov, const float* __restrict__ b_cov,
    const float* __restrict__ w_cum, const float* __restrict__ b_cum,
    const float* __restrict__ w_logit, const float* __restrict__ b_logit,
    const float* __restrict__ w_c1,  const float* __restrict__ b_c1,
    const float* __restrict__ w_c2,  const float* __restrict__ b_c2,
    float* __restrict__ ws, float* __restrict__ d_out)
{
  const int tid  = threadIdx.x;
  const int lane = tid & 63;
  const int wv   = tid >> 6;

  float* out_pred = d_out;              // [512][16]
  float* out_att  = d_out + 8192;       // [512][16][512]

  __shared__ __align__(16) float proj_l[32*256];
  __shared__ __align__(16) float fstage[256][9];
  __shared__ float h1s[256], h2s[256];
  __shared__ __align__(16) float query_s[256];
  __shared__ float cbuf[2][256];
  __shared__ float ctxP[256];
  __shared__ float saw_s[40], csaw_s[40];
  __shared__ float gh1_l[48], gh2_l[48], gi2_l[48], gi1_s[48], h1n_l[16], tanh_l[16];
  __shared__ float logit_s[512];
  __shared__ float wc2s[4][16];
  __shared__ int   sh_g, sh_j, modev;

  // ---- dynamic XCD-aware grouping: rank blocks by (xcc_id, blockIdx) ----
  if (tid == 0){
    unsigned xcc;
    asm volatile("s_getreg_b32 %0, hwreg(HW_REG_XCC_ID)" : "=s"(xcc));
    xcc &= 7u;
    int* table = (int*)(ws + OFF_TBL);
    unsigned* cnt = (unsigned*)(ws + OFF_CNT2);
    __hip_atomic_store(&table[blockIdx.x], (int)xcc, __ATOMIC_RELAXED, __HIP_MEMORY_SCOPE_SYSTEM);
    __hip_atomic_fetch_add(cnt, 1u, __ATOMIC_ACQ_REL, __HIP_MEMORY_SCOPE_SYSTEM);
    while (__hip_atomic_load(cnt, __ATOMIC_ACQUIRE, __HIP_MEMORY_SCOPE_SYSTEM) < 256u)
      __builtin_amdgcn_s_sleep(2);
    int my = (int)xcc, pos = 0;
    for (int b = 0; b < 256; ++b){
      int x = __hip_atomic_load(&table[b], __ATOMIC_RELAXED, __HIP_MEMORY_SCOPE_SYSTEM);
      if (x < my || (x == my && b < (int)blockIdx.x)) ++pos;
    }
    sh_g = pos >> 4;   // group == batch
    sh_j = pos & 15;   // wg slot in group
  }
  __syncthreads();
  const int g = sh_g;
  const int j = sh_j;

  // ---- fast-path visibility probe (plain store -> sc0 load), per group ----
  bool fast;
  {
    unsigned* prb = (unsigned*)(ws + OFF_PRB);
    unsigned* vrd = (unsigned*)(ws + OFF_VRD);
    if (tid == 0){ prb[g*16 + j] = 0xC0FFEEu; store_fence(); }
    int ok = 1;
    if (tid < 16){
      ok = 0;
      for (int it = 0; it < 3000; ++it){
        if (ld_u32_sc0(prb + g*16 + tid) == 0xC0FFEEu){ ok = 1; break; }
        __builtin_amdgcn_s_sleep(1);
      }
    }
    unsigned long long bal = __ballot(tid < 16 ? (ok != 0) : true);
    int wgok = ((bal & 0xFFFFull) == 0xFFFFull) ? 1 : 0;
    if (tid == 0)
      __hip_atomic_store(vrd + g*16 + j, 1u + (unsigned)wgok, __ATOMIC_RELAXED, __HIP_MEMORY_SCOPE_SYSTEM);
    if (tid < 16){
      unsigned v;
      while ((v = __hip_atomic_load(vrd + g*16 + tid, __ATOMIC_RELAXED, __HIP_MEMORY_SCOPE_SYSTEM)) == 0u)
        __builtin_amdgcn_s_sleep(1);
      ok = (v == 2u) ? 1 : 0;
    }
    bal = __ballot(tid < 16 ? (ok != 0) : true);
    if (tid == 0) modev = ((bal & 0xFFFFull) == 0xFFFFull) ? 1 : 0;
    __syncthreads();
    fast = (modev != 0);
  }

  // ---- per-thread register weights ----
  float wcov[4][7], wcum[4][7], wl[4];
  #pragma unroll
  for (int u=0; u<4; ++u){
    int p = 4*lane + u;
    wl[u] = w_logit[p];
    #pragma unroll
    for (int k=0; k<7; ++k){ wcov[u][k] = w_cov[p*7+k]; wcum[u][k] = w_cum[p*7+k]; }
  }
  const float blog = b_logit[0];
  const float bc20 = b_c2[0], bc21 = b_c2[1], bc22 = b_c2[2], bc23 = b_c2[3];

  const int ol = tid >> 2;
  const int qq = tid & 3;
  int grow = 0; float bh1=0.f, bh2=0.f, bi1=0.f, bi2=0.f;
  float wh1[64], wih1[64], wh2[64], wih2[64];
  if (ol < 48){
    int gate = ol >> 4, u = ol & 15;
    grow = gate*256 + 16*j + u;
    bh1 = b_hh1[grow]; bh2 = b_hh2[grow];
    bi1 = b_ih1[grow]; bi2 = b_ih2[grow];
    #pragma unroll
    for (int i=0; i<64; ++i){
      wh1[i]  = w_hh1[(size_t)grow*256 + qq + 4*i];
      wih1[i] = w_ih1[(size_t)grow*256 + qq + 4*i];
      wh2[i]  = w_hh2[(size_t)grow*256 + qq + 4*i];
      wih2[i] = w_ih2[(size_t)grow*256 + qq + 4*i];
    }
  } else {
    #pragma unroll
    for (int i=0; i<64; ++i){ wh1[i]=0.f; wih1[i]=0.f; wh2[i]=0.f; wih2[i]=0.f; }
  }
  float wqr[16];
  #pragma unroll
  for (int i=0; i<16; ++i) wqr[i] = w_q[(size_t)tid*512 + 256 + 16*j + i];

  const int c_ol = tid >> 4, c_qp = tid & 15;
  const int prow = 16*j + c_ol;
  float wc1r[16], wcc[16], wcp[16], wqc[16];
  #pragma unroll
  for (int i=0; i<16; ++i){
    wc1r[i] = w_c1[(size_t)prow*768 + 512 + c_qp + 16*i];
    wcc[i]  = w_c1[(size_t)prow*768 +   0 + c_qp + 16*i];
    wcp[i]  = w_c1[(size_t)prow*768 + 256 + c_qp + 16*i];
    wqc[i]  = w_q [(size_t)prow*512 +   0 + c_qp + 16*i];
  }
  const float bcl = b_c1[prow];
  const float bqc = b_q[prow] + b_cov[prow] + b_cum[prow];

  if (tid < 64) wc2s[tid>>4][tid&15] = w_c2[(tid>>4)*256 + 16*j + (tid&15)];
  if (tid < 40){ saw_s[tid] = 0.f; csaw_s[tid] = 0.f; }

  // ---- prologue: ctx(0), proj slice, gi1(0), qc(0) ----
  cbuf[0][tid] = feats[(size_t)(g*256 + tid)*512 + 0];
  {
    const float* fr = feats + ((size_t)(g*256 + tid))*512;
    const float* wr = w_fp + (size_t)tid*256;
    const float bfp = b_fp[tid];
    for (int z=0; z<4; ++z){
      for (int cc=0; cc<8; ++cc){
        int pos = 32*j + 8*z + cc;
        fstage[tid][cc] = (pos >= 1) ? fr[pos-1] : 0.f;
      }
      __syncthreads();
      float pacc[8] = {0,0,0,0,0,0,0,0};
      for (int c=0; c<256; ++c){
        float w = wr[c];
        #pragma unroll
        for (int cc=0; cc<8; ++cc) pacc[cc] += w * fstage[c][cc];
      }
      __syncthreads();
      #pragma unroll
      for (int cc=0; cc<8; ++cc) proj_l[(8*z+cc)*256 + tid] = pacc[cc] + bfp;
    }
  }
  __syncthreads();
  if (ol < 48){                               // gi1(0) -> LDS
    float s = 0.f;
    #pragma unroll
    for (int i=0; i<64; ++i) s += wih1[i]*cbuf[0][qq + 4*i];
    s += __shfl_xor(s, 1, 64); s += __shfl_xor(s, 2, 64);
    if (qq == 0) gi1_s[ol] = s + bi1;
  }
  {                                            // qc(0)
    float s = 0.f;
    #pragma unroll
    for (int i=0; i<16; ++i) s += wqc[i]*cbuf[0][c_qp + 16*i];
    s += __shfl_xor(s, 1, 64); s += __shfl_xor(s, 2, 64);
    s += __shfl_xor(s, 4, 64); s += __shfl_xor(s, 8, 64);
    if (c_qp == 0) stx(ws + OFF_QCS + 0*4096 + g*256 + prow, s + bqc, fast);
  }
  __syncthreads();

  unsigned* flg = (unsigned*)(ws + OFF_FLG) + g*16;
  unsigned ep = 0;
  float cls_ctx = 0.f;

  for (int t = 0; t <= 512; ++t){
    // ================= P0 =================
    h2s[tid] = ldx(ws + OFF_H2 + g*256 + tid, fast);
    if (t < 511) cbuf[(t+1)&1][tid] = feats[(size_t)(g*256 + tid)*512 + (t+1)];
    __syncthreads();
    if (t < 512 && ol < 48){                   // gh1(t)
      float s = 0.f;
      #pragma unroll
      for (int i=0; i<64; ++i) s += wh1[i]*h2s[qq + 4*i];
      s += __shfl_xor(s, 1, 64); s += __shfl_xor(s, 2, 64);
      if (qq == 0) gh1_l[ol] = s + bh1;
    }
    if (t >= 1){                               // cls(t-1) tanh rows
      float s = 0.f;
      #pragma unroll
      for (int i=0; i<16; ++i){
        int d = c_qp + 16*i;
        s += wc1r[i]*h2s[d] + wcp[i]*ctxP[d];
      }
      s += __shfl_xor(s, 1, 64); s += __shfl_xor(s, 2, 64);
      s += __shfl_xor(s, 4, 64); s += __shfl_xor(s, 8, 64);
      if (c_qp == 0) tanh_l[c_ol] = tanh_fast(s + cls_ctx + bcl);
    }
    __syncthreads();
    if (t < 512 && tid < 16){                  // h1(t) own rows
      int ig = 16*j + tid;
      float r  = sigm_fast(gi1_s[tid]      + gh1_l[tid]);
      float z  = sigm_fast(gi1_s[16 + tid] + gh1_l[16 + tid]);
      float nn = tanh_fast(gi1_s[32 + tid] + r*gh1_l[32 + tid]);
      float h1v = (1.f - z)*nn + z*h2s[ig];
      stx(ws + OFF_H1 + g*256 + ig, h1v, fast);
      h1n_l[tid] = h1v;
    }
    if (t >= 1 && tid < 4){                    // cls partial out
      float sum = 0.f;
      #pragma unroll
      for (int o=0; o<16; ++o) sum += wc2s[tid][o]*tanh_l[o];
      stx(ws + OFF_CLSP + (g*16 + j)*4 + tid, sum, fast);
    }
    __syncthreads();
    if (t < 512){                              // qh partial (transposed layout)
      float s = 0.f;
      #pragma unroll
      for (int i=0; i<16; ++i) s += wqr[i]*h1n_l[i];
      stx(ws + OFF_QHPT + (size_t)g*4096 + tid*16 + j, s, fast);
    }
    bar_arrive(flg, j, ++ep, fast);            // BAR A arrive
    if (t < 511){                              // window: gi1(t+1), qc(t+1)
      const float* cN = cbuf[(t+1)&1];
      if (ol < 48){
        float s = 0.f;
        #pragma unroll
        for (int i=0; i<64; ++i) s += wih1[i]*cN[qq + 4*i];
        s += __shfl_xor(s, 1, 64); s += __shfl_xor(s, 2, 64);
        if (qq == 0) gi1_s[ol] = s + bi1;
      }
      {
        float s = 0.f;
        #pragma unroll
        for (int i=0; i<16; ++i) s += wqc[i]*cN[c_qp + 16*i];
        s += __shfl_xor(s, 1, 64); s += __shfl_xor(s, 2, 64);
        s += __shfl_xor(s, 4, 64); s += __shfl_xor(s, 8, 64);
        if (c_qp == 0) stx(ws + OFF_QCS + (size_t)((t+1)&1)*4096 + g*256 + prow, s + bqc, fast);
      }
    }
    bar_wait(flg, ep, fast);                   // BAR A wait
    // ================= P1 =================
    float lgv[8];
    if (t < 512){
      h1s[tid] = ldx(ws + OFF_H1 + g*256 + tid, fast);
      float q = ldx(ws + OFF_QCS + (size_t)(t&1)*4096 + g*256 + tid, fast);
      const float* qp = ws + OFF_QHPT + (size_t)g*4096 + tid*16;
      if (fast){
        float4 a,b,c,d;
        ld4x4_sc0(qp, a, b, c, d);
        q += (a.x+a.y+a.z+a.w) + (b.x+b.y+b.z+b.w) + (c.x+c.y+c.z+c.w) + (d.x+d.y+d.z+d.w);
      } else {
        #pragma unroll
        for (int jj=0; jj<16; ++jj)
          q += __hip_atomic_load((float*)(qp+jj), __ATOMIC_RELAXED, __HIP_MEMORY_SCOPE_SYSTEM);
      }
      query_s[tid] = q;
    }
    __syncthreads();
    if (t < 512){
      float qv[4];
      { float4 q4 = *(const float4*)&query_s[4*lane]; qv[0]=q4.x; qv[1]=q4.y; qv[2]=q4.z; qv[3]=q4.w; }
      #pragma unroll
      for (int i=0; i<8; ++i){
        int ln = 8*wv + i;
        int n  = 32*j + ln;
        float4 pj = *(const float4*)&proj_l[ln*256 + 4*lane];
        float pv[4] = {pj.x, pj.y, pj.z, pj.w};
        float sw[7], cw[7];
        #pragma unroll
        for (int k=0; k<7; ++k){ sw[k] = saw_s[ln+k]; cw[k] = csaw_s[ln+k]; }
        float s = 0.f;
        #pragma unroll
        for (int u=0; u<4; ++u){
          float f = pv[u] + qv[u];
          #pragma unroll
          for (int k=0; k<7; ++k) f += wcov[u][k]*sw[k] + wcum[u][k]*cw[k];
          s += wl[u]*tanh_fast(f);
        }
        #pragma unroll
        for (int mm=32; mm>=1; mm>>=1) s += __shfl_xor(s, mm, 64);
        float lg = s + blog;
        lgv[i] = lg;
        if (lane == 0) stx(ws + OFF_LOG + g*512 + n, lg, fast);
      }
      if (ol < 48){                            // gh2(t)
        float s = 0.f;
        #pragma unroll
        for (int i=0; i<64; ++i) s += wh2[i]*h1s[qq + 4*i];
        s += __shfl_xor(s, 1, 64); s += __shfl_xor(s, 2, 64);
        if (qq == 0) gh2_l[ol] = s + bh2;
      }
    }
    bar_arrive(flg, j, ++ep, fast);            // BAR B arrive
    if (t < 512 && lane == 0){                 // window: out_att
      #pragma unroll
      for (int i=0; i<8; ++i)
        out_att[((size_t)t*16 + g)*512 + 32*j + 8*wv + i] = lgv[i];
    }
    if (t >= 1 && j == 0 && wv == 0){          // window: pred(t-1) finalize
      float v = ldx(ws + OFF_CLSP + g*64 + lane, fast);
      #pragma unroll
      for (int d2=4; d2<64; d2<<=1) v += __shfl_xor(v, d2, 64);
      float v0 = __shfl(v, 0, 64), v1 = __shfl(v, 1, 64);
      float v2 = __shfl(v, 2, 64), v3 = __shfl(v, 3, 64);
      if (lane == 0){
        v0 += bc20; v1 += bc21; v2 += bc22; v3 += bc23;
        int pb = 0; float bv = v0;
        if (v1 > bv){ bv = v1; pb = 1; }
        if (v2 > bv){ bv = v2; pb = 2; }
        if (v3 > bv){ bv = v3; pb = 3; }
        out_pred[(t-1)*16 + g] = (float)pb;
      }
    }
    bar_wait(flg, ep, fast);                   // BAR B wait
    // ================= P2 =================
    if (t < 512){
      logit_s[tid]       = ldx(ws + OFF_LOG + g*512 + tid, fast);
      logit_s[tid + 256] = ldx(ws + OFF_LOG + g*512 + tid + 256, fast);
      __syncthreads();
      float mx; int idx; float invZ;
      {
        float m = -3.0e38f; int mi = 0;
        #pragma unroll
        for (int k=0; k<8; ++k){
          int n = lane + 64*k;
          float vv = (n <= t) ? logit_s[n] : -3.0e38f;
          if (vv > m){ m = vv; mi = n; }
        }
        #pragma unroll
        for (int d2=1; d2<64; d2<<=1){
          float om = __shfl_xor(m, d2, 64); int oi = __shfl_xor(mi, d2, 64);
          if (om > m || (om == m && oi < mi)){ m = om; mi = oi; }
        }
        float z = 0.f;
        #pragma unroll
        for (int k=0; k<8; ++k){
          int n = lane + 64*k;
          if (n <= t) z += __expf(logit_s[n] - m);
        }
        #pragma unroll
        for (int d2=1; d2<64; d2<<=1) z += __shfl_xor(z, d2, 64);
        mx = m; idx = mi; invZ = 1.f/z;
      }
      if (tid < 40){
        int r = 32*j - 3 + tid;
        float a = 0.f;
        if (r >= 0 && r <= t) a = __expf(logit_s[r] - mx)*invZ;
        saw_s[tid] = a;
        csaw_s[tid] += a;
      }
      ctxP[tid] = (idx >= 1) ? feats[(size_t)(g*256 + tid)*512 + idx - 1] : 0.f;
      __syncthreads();
      if (ol < 48){                            // gi2(t)
        float s = 0.f;
        #pragma unroll
        for (int i=0; i<64; ++i) s += wih2[i]*ctxP[qq + 4*i];
        s += __shfl_xor(s, 1, 64); s += __shfl_xor(s, 2, 64);
        if (qq == 0) gi2_l[ol] = s + bi2;
      }
      __syncthreads();
      if (tid < 16){                           // h2(t) own rows
        int ig = 16*j + tid;
        float r  = sigm_fast(gi2_l[tid]      + gh2_l[tid]);
        float z  = sigm_fast(gi2_l[16 + tid] + gh2_l[16 + tid]);
        float nn = tanh_fast(gi2_l[32 + tid] + r*gh2_l[32 + tid]);
        stx(ws + OFF_H2 + g*256 + ig, (1.f - z)*nn + z*h1s[ig], fast);
      }
    }
    bar_arrive(flg, j, ++ep, fast);            // BAR C arrive
    if (t < 512){                              // window: cls ctx part for cls(t)
      const float* cT = cbuf[t&1];
      float s = 0.f;
      #pragma unroll
      for (int i=0; i<16; ++i) s += wcc[i]*cT[c_qp + 16*i];
      s += __shfl_xor(s, 1, 64); s += __shfl_xor(s, 2, 64);
      s += __shfl_xor(s, 4, 64); s += __shfl_xor(s, 8, 64);
      cls_ctx = s;
    }
    bar_wait(flg, ep, fast);                   // BAR C wait
  }
}

extern "C" void kernel_launch(void* const* d_in, const int* in_sizes, int n_in,
                              void* d_out, int out_size, void* d_ws, size_t ws_size,
                              hipStream_t stream)
{
  (void)in_sizes; (void)n_in; (void)out_size; (void)ws_size;
  const float* feats   = (const float*)d_in[0];
  const float* w_fp    = (const float*)d_in[2];
  const float* b_fp    = (const float*)d_in[3];
  const float* w_si    = (const float*)d_in[4];
  const float* b_si    = (const float*)d_in[5];
  const float* w_ih1   = (const float*)d_in[6];
  const float* w_hh1   = (const float*)d_in[7];
  const float* b_ih1   = (const float*)d_in[8];
  const float* b_hh1   = (const float*)d_in[9];
  const float* w_ih2   = (const float*)d_in[10];
  const float* w_hh2   = (const float*)d_in[11];
  const float* b_ih2   = (const float*)d_in[12];
  const float* b_hh2   = (const float*)d_in[13];
  const float* w_q     = (const float*)d_in[14];
  const float* b_q     = (const float*)d_in[15];
  const float* w_cov   = (const float*)d_in[16];
  const float* b_cov   = (const float*)d_in[17];
  const float* w_cum   = (const float*)d_in[18];
  const float* b_cum   = (const float*)d_in[19];
  const float* w_logit = (const float*)d_in[20];
  const float* b_logit = (const float*)d_in[21];
  const float* w_c1    = (const float*)d_in[22];
  const float* b_c1    = (const float*)d_in[23];
  const float* w_c2    = (const float*)d_in[24];
  const float* b_c2    = (const float*)d_in[25];
  float* ws  = (float*)d_ws;
  float* out = (float*)d_out;

  init_k<<<1, 256, 0, stream>>>(ws);
  state0_k<<<16, 256, 0, stream>>>(feats, w_si, b_si, ws);
  persist_k<<<256, 256, 0, stream>>>(feats, w_fp, b_fp, w_ih1, b_ih1,
                                     w_hh1, b_hh1, w_ih2, b_ih2, w_hh2, b_hh2,
                                     w_q, b_q, w_cov, b_cov, w_cum, b_cum,
                                     w_logit, b_logit, w_c1, b_c1, w_c2, b_c2,
                                     ws, out);
}

// Round 9
// 10004.874 us; speedup vs baseline: 6.2670x; 1.1953x over previous
//
#include <hip/hip_runtime.h>

typedef unsigned short u16;

// ---------------- workspace layout (float units) ----------------
// GI2 table (bf16): [513 cols][16 g][768] = 6,303,744 u16 = 3,151,872 floats
#define OFF_T2    0ull
#define OFF_H0    3151872ull   // [16][256] state0
#define OFF_H1    3155968ull   // [16][256]
#define OFF_GH2   3160064ull   // [16][768]
#define OFF_QCS   3172352ull   // [2][16][256]
#define OFF_QHPT  3180544ull   // [16][256][16] transposed qh partials
#define OFF_CLSP  3246080ull   // [16][16][4]
#define OFF_LOG   3247104ull   // [16][512]
#define OFF_FLG   3255296ull   // [16][16] u32 epoch flags
// total ~3,255,552 floats = 13.0 MB

__device__ __forceinline__ float b2f(u16 u){
  union { unsigned int i; float f; } x; x.i = ((unsigned int)u) << 16; return x.f;
}
__device__ __forceinline__ u16 f2b(float f){
  union { float f; unsigned int i; } x; x.f = f;
  unsigned int lsb = (x.i >> 16) & 1u;
  unsigned int r = x.i + 0x7fffu + lsb;
  return (u16)(r >> 16);
}
__device__ __forceinline__ float tanh_fast(float x){
  float e = __expf(2.f*x);
  return 1.f - 2.f/(e + 1.f);
}
__device__ __forceinline__ float sigm_fast(float x){
  return 1.f/(1.f + __expf(-x));
}
// proven comm primitives (round 6): agent-scope relaxed atomics
__device__ __forceinline__ float ldc(const float* p){
  return __hip_atomic_load((float*)p, __ATOMIC_RELAXED, __HIP_MEMORY_SCOPE_AGENT);
}
__device__ __forceinline__ void stc(float* p, float v){
  __hip_atomic_store(p, v, __ATOMIC_RELAXED, __HIP_MEMORY_SCOPE_AGENT);
}

// ---------------- init: zero barrier flags ----------------
__global__ void init_k(float* __restrict__ ws){
  unsigned* flg = (unsigned*)(ws + OFF_FLG);
  if (threadIdx.x < 256) flg[threadIdx.x] = 0u;
}

// ---------------- state0 ----------------
__global__ void state0_k(const float* __restrict__ feats, const float* __restrict__ w_si,
                         const float* __restrict__ b_si, float* __restrict__ ws){
  const int b = blockIdx.x, tid = threadIdx.x;
  __shared__ float S[256];
  const float* row = feats + ((size_t)(b*256 + tid))*512;
  float a0=0.f,a1=0.f,a2=0.f,a3=0.f;
  for (int n=0;n<512;n+=4){ a0+=row[n]; a1+=row[n+1]; a2+=row[n+2]; a3+=row[n+3]; }
  S[tid] = (a0+a1)+(a2+a3);
  __syncthreads();
  const float* wr = w_si + (size_t)tid*256;
  float acc = 0.f;
  for (int c=0;c<256;c++) acc += wr[c]*S[c];
  ws[OFF_H0 + b*256 + tid] = acc/513.f + b_si[tid];
}

// ---------------- GI2 table: gi2(col) = W_ih2 @ feats_p[:,col] + b_ih2, bf16 ----------------
__global__ __launch_bounds__(256,2) void precomp_k(
    const float* __restrict__ feats,
    const float* __restrict__ w_ih2, const float* __restrict__ b_ih2,
    float* __restrict__ ws)
{
  const int xc = blockIdx.x;     // 0..16 col chunk of 32 (513 cols)
  const int b  = blockIdx.y;
  const int tid = threadIdx.x;
  __shared__ __align__(16) float fc[256][36];
  {
    const float* fr = feats + ((size_t)(b*256 + tid))*512;
    for (int xx=0; xx<32; ++xx){
      int col = xc*32 + xx;
      fc[tid][xx] = (col >= 1 && col <= 512) ? fr[col-1] : 0.f;
    }
  }
  __syncthreads();
  const float* r0 = w_ih2 + (size_t)tid*256;
  const float* r1 = w_ih2 + (size_t)(tid+256)*256;
  const float* r2 = w_ih2 + (size_t)(tid+512)*256;
  float bb0 = b_ih2[tid], bb1 = b_ih2[tid+256], bb2 = b_ih2[tid+512];
  float acc0[32], acc1[32], acc2[32];
  #pragma unroll
  for (int xx=0; xx<32; ++xx){ acc0[xx]=bb0; acc1[xx]=bb1; acc2[xx]=bb2; }
  for (int c=0; c<256; ++c){
    float w0 = r0[c], w1 = r1[c], w2 = r2[c];
    const float* cb = &fc[c][0];
    #pragma unroll
    for (int xx=0; xx<32; ++xx){ acc0[xx]+=w0*cb[xx]; acc1[xx]+=w1*cb[xx]; acc2[xx]+=w2*cb[xx]; }
  }
  u16* tbl = (u16*)(ws + OFF_T2);
  for (int xx=0; xx<32; ++xx){
    int col = xc*32 + xx;
    if (col > 512) continue;
    size_t base = ((size_t)col*16 + b)*768;
    tbl[base + tid]       = f2b(acc0[xx]);
    tbl[base + 256 + tid] = f2b(acc1[xx]);
    tbl[base + 512 + tid] = f2b(acc2[xx]);
  }
}

// ---------------- split barrier, leader-only poll ----------------
__device__ __forceinline__ void bar_arrive(unsigned* flg, int j, unsigned ep){
  __builtin_amdgcn_s_waitcnt(0);   // drain this wave's stores
  __syncthreads();                 // whole wg drained
  if (threadIdx.x == 0)
    __hip_atomic_store(flg + j, ep, __ATOMIC_RELAXED, __HIP_MEMORY_SCOPE_AGENT);
}
__device__ __forceinline__ void bar_wait(unsigned* flg, unsigned ep){
  if (threadIdx.x == 0){
    for (;;){
      bool ok = true;
      #pragma unroll
      for (int i=0; i<16; ++i)
        ok &= (__hip_atomic_load(flg + i, __ATOMIC_RELAXED, __HIP_MEMORY_SCOPE_AGENT) >= ep);
      if (ok) break;
      __builtin_amdgcn_s_sleep(2);
    }
  }
  __syncthreads();
}

// ---------------- persistent scan kernel: 2 barriers/step ----------------
__global__ __launch_bounds__(256, 1) void persist_k(
    const float* __restrict__ feats,
    const float* __restrict__ w_fp,  const float* __restrict__ b_fp,
    const float* __restrict__ w_ih1, const float* __restrict__ b_ih1,
    const float* __restrict__ w_hh1, const float* __restrict__ b_hh1,
    const float* __restrict__ w_hh2, const float* __restrict__ b_hh2,
    const float* __restrict__ w_q,   const float* __restrict__ b_q,
    const float* __restrict__ w_cov, const float* __restrict__ b_cov,
    const float* __restrict__ w_cum, const float* __restrict__ b_cum,
    const float* __restrict__ w_logit, const float* __restrict__ b_logit,
    const float* __restrict__ w_c1,  const float* __restrict__ b_c1,
    const float* __restrict__ w_c2,  const float* __restrict__ b_c2,
    float* __restrict__ ws, float* __restrict__ d_out)
{
  const int tid  = threadIdx.x;
  const int g    = blockIdx.x & 15;
  const int j    = blockIdx.x >> 4;
  const int lane = tid & 63;
  const int wv   = tid >> 6;

  float* out_pred = d_out;              // [512][16]
  float* out_att  = d_out + 8192;       // [512][16][512]
  const u16* tbl2 = (const u16*)(ws + OFF_T2);

  __shared__ __align__(16) float proj_l[32*256];
  __shared__ __align__(16) float fstage[256][9];
  __shared__ float h1s[256], h2s[256];
  __shared__ __align__(16) float query_s[256];
  __shared__ float cbuf[2][256];
  __shared__ float ctxP[256];
  __shared__ float saw_s[40], csaw_s[40];
  __shared__ float gh1_l[48], gi1_s[48], h1n_l[16], tanh_l[16];
  __shared__ float logit_s[512];
  __shared__ float wc2s[4][16];

  // ---- register weights ----
  float wcov[4][7], wcum[4][7], wl[4];
  #pragma unroll
  for (int u=0; u<4; ++u){
    int p = 4*lane + u;
    wl[u] = w_logit[p];
    #pragma unroll
    for (int k=0; k<7; ++k){ wcov[u][k] = w_cov[p*7+k]; wcum[u][k] = w_cum[p*7+k]; }
  }
  const float blog = b_logit[0];
  const float bc20 = b_c2[0], bc21 = b_c2[1], bc22 = b_c2[2], bc23 = b_c2[3];

  const int ol = tid >> 2;
  const int qq = tid & 3;
  int grow = 0; float bh1=0.f, bh2=0.f, bi1=0.f;
  float wh1[64], wih1[64], wh2[64];
  if (ol < 48){
    int gate = ol >> 4, u = ol & 15;
    grow = gate*256 + 16*j + u;
    bh1 = b_hh1[grow]; bh2 = b_hh2[grow]; bi1 = b_ih1[grow];
    #pragma unroll
    for (int i=0; i<64; ++i){
      wh1[i]  = w_hh1[(size_t)grow*256 + qq + 4*i];
      wih1[i] = w_ih1[(size_t)grow*256 + qq + 4*i];
      wh2[i]  = w_hh2[(size_t)grow*256 + qq + 4*i];
    }
  } else {
    #pragma unroll
    for (int i=0; i<64; ++i){ wh1[i]=0.f; wih1[i]=0.f; wh2[i]=0.f; }
  }
  float wqr[16];
  #pragma unroll
  for (int i=0; i<16; ++i) wqr[i] = w_q[(size_t)tid*512 + 256 + 16*j + i];

  const int c_ol = tid >> 4, c_qp = tid & 15;
  const int prow = 16*j + c_ol;
  float wc1r[16], wcc[16], wcp[16], wqc[16];
  #pragma unroll
  for (int i=0; i<16; ++i){
    wc1r[i] = w_c1[(size_t)prow*768 + 512 + c_qp + 16*i];
    wcc[i]  = w_c1[(size_t)prow*768 +   0 + c_qp + 16*i];
    wcp[i]  = w_c1[(size_t)prow*768 + 256 + c_qp + 16*i];
    wqc[i]  = w_q [(size_t)prow*512 +   0 + c_qp + 16*i];
  }
  const float bcl = b_c1[prow];
  const float bqc = b_q[prow] + b_cov[prow] + b_cum[prow];

  if (tid < 64) wc2s[tid>>4][tid&15] = w_c2[(tid>>4)*256 + 16*j + (tid&15)];
  if (tid < 40){ saw_s[tid] = 0.f; csaw_s[tid] = 0.f; }

  // ---- prologue ----
  cbuf[0][tid] = feats[(size_t)(g*256 + tid)*512 + 0];
  h2s[tid] = ws[OFF_H0 + g*256 + tid];
  {
    const float* fr = feats + ((size_t)(g*256 + tid))*512;
    const float* wr = w_fp + (size_t)tid*256;
    const float bfp = b_fp[tid];
    for (int z=0; z<4; ++z){
      for (int cc=0; cc<8; ++cc){
        int pos = 32*j + 8*z + cc;
        fstage[tid][cc] = (pos >= 1) ? fr[pos-1] : 0.f;
      }
      __syncthreads();
      float pacc[8] = {0,0,0,0,0,0,0,0};
      for (int c=0; c<256; ++c){
        float w = wr[c];
        #pragma unroll
        for (int cc=0; cc<8; ++cc) pacc[cc] += w * fstage[c][cc];
      }
      __syncthreads();
      #pragma unroll
      for (int cc=0; cc<8; ++cc) proj_l[(8*z+cc)*256 + tid] = pacc[cc] + bfp;
    }
  }
  __syncthreads();
  if (ol < 48){                // gh1(0), gi1(0)
    float s1 = 0.f, s2 = 0.f;
    #pragma unroll
    for (int i=0; i<64; ++i){
      s1 += wh1[i]*h2s[qq + 4*i];
      s2 += wih1[i]*cbuf[0][qq + 4*i];
    }
    s1 += __shfl_xor(s1, 1, 64); s1 += __shfl_xor(s1, 2, 64);
    s2 += __shfl_xor(s2, 1, 64); s2 += __shfl_xor(s2, 2, 64);
    if (qq == 0){ gh1_l[ol] = s1 + bh1; gi1_s[ol] = s2 + bi1; }
  }
  __syncthreads();
  if (tid < 16){               // h1(0)
    int ig = 16*j + tid;
    float r  = sigm_fast(gi1_s[tid]      + gh1_l[tid]);
    float z  = sigm_fast(gi1_s[16 + tid] + gh1_l[16 + tid]);
    float nn = tanh_fast(gi1_s[32 + tid] + r*gh1_l[32 + tid]);
    float h1v = (1.f - z)*nn + z*h2s[ig];
    stc(ws + OFF_H1 + g*256 + ig, h1v);
    h1n_l[tid] = h1v;
  }
  __syncthreads();
  {                            // qh partial (0)
    float s = 0.f;
    #pragma unroll
    for (int i=0; i<16; ++i) s += wqr[i]*h1n_l[i];
    stc(ws + OFF_QHPT + (size_t)g*4096 + tid*16 + j, s);
  }
  {                            // qc(0)
    float s = 0.f;
    #pragma unroll
    for (int i=0; i<16; ++i) s += wqc[i]*cbuf[0][c_qp + 16*i];
    s += __shfl_xor(s, 1, 64); s += __shfl_xor(s, 2, 64);
    s += __shfl_xor(s, 4, 64); s += __shfl_xor(s, 8, 64);
    if (c_qp == 0) stc(ws + OFF_QCS + 0*4096 + g*256 + prow, s + bqc);
  }

  unsigned* flg = (unsigned*)(ws + OFF_FLG) + g*16;
  unsigned ep = 0;
  bar_arrive(flg, j, ++ep); bar_wait(flg, ep);   // BAR A (prologue)

  for (int t = 0; t <= 512; ++t){
    // ================= P1 =================
    float lgv[8];
    if (t < 512){
      h1s[tid] = ldc(ws + OFF_H1 + g*256 + tid);
      float q = ldc(ws + OFF_QCS + (size_t)(t&1)*4096 + g*256 + tid);
      const float* qp = ws + OFF_QHPT + (size_t)g*4096 + tid*16;
      #pragma unroll
      for (int jj=0; jj<16; ++jj) q += ldc(qp + jj);
      query_s[tid] = q;
      __syncthreads();
      float qv[4];
      { float4 q4 = *(const float4*)&query_s[4*lane]; qv[0]=q4.x; qv[1]=q4.y; qv[2]=q4.z; qv[3]=q4.w; }
      #pragma unroll
      for (int i=0; i<8; ++i){
        int ln = 8*wv + i;
        int n  = 32*j + ln;
        float4 pj = *(const float4*)&proj_l[ln*256 + 4*lane];
        float pv[4] = {pj.x, pj.y, pj.z, pj.w};
        float sw[7], cw[7];
        #pragma unroll
        for (int k=0; k<7; ++k){ sw[k] = saw_s[ln+k]; cw[k] = csaw_s[ln+k]; }
        float s = 0.f;
        #pragma unroll
        for (int u=0; u<4; ++u){
          float f = pv[u] + qv[u];
          #pragma unroll
          for (int k=0; k<7; ++k) f += wcov[u][k]*sw[k] + wcum[u][k]*cw[k];
          s += wl[u]*tanh_fast(f);
        }
        #pragma unroll
        for (int mm=32; mm>=1; mm>>=1) s += __shfl_xor(s, mm, 64);
        float lg = s + blog;
        lgv[i] = lg;
        if (lane == 0) stc(ws + OFF_LOG + g*512 + n, lg);
      }
      if (ol < 48){                            // gh2(t) own rows
        float s = 0.f;
        #pragma unroll
        for (int i=0; i<64; ++i) s += wh2[i]*h1s[qq + 4*i];
        s += __shfl_xor(s, 1, 64); s += __shfl_xor(s, 2, 64);
        if (qq == 0) stc(ws + OFF_GH2 + g*768 + grow, s + bh2);
      }
    }
    if (t >= 1 && j == 0 && wv == 0){          // pred(t-1) finalize
      float v = ldc(ws + OFF_CLSP + g*64 + lane);
      #pragma unroll
      for (int d2=4; d2<64; d2<<=1) v += __shfl_xor(v, d2, 64);
      float v0 = __shfl(v, 0, 64), v1 = __shfl(v, 1, 64);
      float v2 = __shfl(v, 2, 64), v3 = __shfl(v, 3, 64);
      if (lane == 0){
        v0 += bc20; v1 += bc21; v2 += bc22; v3 += bc23;
        int pb = 0; float bv = v0;
        if (v1 > bv){ bv = v1; pb = 1; }
        if (v2 > bv){ bv = v2; pb = 2; }
        if (v3 > bv){ bv = v3; pb = 3; }
        out_pred[(t-1)*16 + g] = (float)pb;
      }
    }
    bar_arrive(flg, j, ++ep);                  // BAR B arrive
    if (t < 512 && lane == 0){                 // window: out_att
      #pragma unroll
      for (int i=0; i<8; ++i)
        out_att[((size_t)t*16 + g)*512 + 32*j + 8*wv + i] = lgv[i];
    }
    bar_wait(flg, ep);                         // BAR B wait
    // ================= P2 =================
    if (t < 512){
      logit_s[tid]       = ldc(ws + OFF_LOG + g*512 + tid);
      logit_s[tid + 256] = ldc(ws + OFF_LOG + g*512 + tid + 256);
      if (t < 511) cbuf[(t+1)&1][tid] = feats[(size_t)(g*256 + tid)*512 + (t+1)];
      __syncthreads();
      // wave-redundant masked softmax/argmax over n<=t
      float mx; int idx; float invZ;
      {
        float m = -3.0e38f; int mi = 0;
        #pragma unroll
        for (int k=0; k<8; ++k){
          int n = lane + 64*k;
          float vv = (n <= t) ? logit_s[n] : -3.0e38f;
          if (vv > m){ m = vv; mi = n; }
        }
        #pragma unroll
        for (int d2=1; d2<64; d2<<=1){
          float om = __shfl_xor(m, d2, 64); int oi = __shfl_xor(mi, d2, 64);
          if (om > m || (om == m && oi < mi)){ m = om; mi = oi; }
        }
        float z = 0.f;
        #pragma unroll
        for (int k=0; k<8; ++k){
          int n = lane + 64*k;
          if (n <= t) z += __expf(logit_s[n] - m);
        }
        #pragma unroll
        for (int d2=1; d2<64; d2<<=1) z += __shfl_xor(z, d2, 64);
        mx = m; idx = mi; invZ = 1.f/z;
      }
      if (tid < 40){
        int r = 32*j - 3 + tid;
        float a = 0.f;
        if (r >= 0 && r <= t) a = __expf(logit_s[r] - mx)*invZ;
        saw_s[tid] = a;
        csaw_s[tid] += a;
      }
      ctxP[tid] = (idx >= 1) ? feats[(size_t)(g*256 + tid)*512 + idx - 1] : 0.f;
      // h2(t) fully local: gh2 full (ws) + gi2 full (table)
      float h2v;
      {
        float hr = ldc(ws + OFF_GH2 + g*768 + tid);
        float hz = ldc(ws + OFF_GH2 + g*768 + 256 + tid);
        float hn = ldc(ws + OFF_GH2 + g*768 + 512 + tid);
        const u16* t2 = tbl2 + ((size_t)idx*16 + g)*768;
        float gr = b2f(t2[tid]), gz = b2f(t2[256 + tid]), gn = b2f(t2[512 + tid]);
        float r = sigm_fast(gr + hr);
        float z = sigm_fast(gz + hz);
        float nn = tanh_fast(gn + r*hn);
        h2v = (1.f - z)*nn + z*h1s[tid];
      }
      __syncthreads();
      h2s[tid] = h2v;
      __syncthreads();
      // cls(t): own tanh rows + partials
      {
        const float* cT = cbuf[t&1];
        float s = 0.f;
        #pragma unroll
        for (int i=0; i<16; ++i){
          int d = c_qp + 16*i;
          s += wc1r[i]*h2s[d] + wcc[i]*cT[d] + wcp[i]*ctxP[d];
        }
        s += __shfl_xor(s, 1, 64); s += __shfl_xor(s, 2, 64);
        s += __shfl_xor(s, 4, 64); s += __shfl_xor(s, 8, 64);
        if (c_qp == 0) tanh_l[c_ol] = tanh_fast(s + bcl);
      }
      // gh1(t+1), gi1(t+1)
      if (t < 511 && ol < 48){
        const float* cN = cbuf[(t+1)&1];
        float s1 = 0.f, s2 = 0.f;
        #pragma unroll
        for (int i=0; i<64; ++i){
          s1 += wh1[i]*h2s[qq + 4*i];
          s2 += wih1[i]*cN[qq + 4*i];
        }
        s1 += __shfl_xor(s1, 1, 64); s1 += __shfl_xor(s1, 2, 64);
        s2 += __shfl_xor(s2, 1, 64); s2 += __shfl_xor(s2, 2, 64);
        if (qq == 0){ gh1_l[ol] = s1 + bh1; gi1_s[ol] = s2 + bi1; }
      }
      __syncthreads();
      if (tid < 4){                            // cls partial out
        float sum = 0.f;
        #pragma unroll
        for (int o=0; o<16; ++o) sum += wc2s[tid][o]*tanh_l[o];
        stc(ws + OFF_CLSP + (g*16 + j)*4 + tid, sum);
      }
      if (t < 511){
        if (tid < 16){                         // h1(t+1) own rows
          int ig = 16*j + tid;
          float r  = sigm_fast(gi1_s[tid]      + gh1_l[tid]);
          float z  = sigm_fast(gi1_s[16 + tid] + gh1_l[16 + tid]);
          float nn = tanh_fast(gi1_s[32 + tid] + r*gh1_l[32 + tid]);
          float h1v = (1.f - z)*nn + z*h2s[ig];
          stc(ws + OFF_H1 + g*256 + ig, h1v);
          h1n_l[tid] = h1v;
        }
        __syncthreads();
        {                                      // qh partial
          float s = 0.f;
          #pragma unroll
          for (int i=0; i<16; ++i) s += wqr[i]*h1n_l[i];
          stc(ws + OFF_QHPT + (size_t)g*4096 + tid*16 + j, s);
        }
        {                                      // qc(t+1)
          const float* cN = cbuf[(t+1)&1];
          float s = 0.f;
          #pragma unroll
          for (int i=0; i<16; ++i) s += wqc[i]*cN[c_qp + 16*i];
          s += __shfl_xor(s, 1, 64); s += __shfl_xor(s, 2, 64);
          s += __shfl_xor(s, 4, 64); s += __shfl_xor(s, 8, 64);
          if (c_qp == 0) stc(ws + OFF_QCS + (size_t)((t+1)&1)*4096 + g*256 + prow, s + bqc);
        }
      }
      bar_arrive(flg, j, ++ep);                // BAR A
      bar_wait(flg, ep);
    }
  }
}

extern "C" void kernel_launch(void* const* d_in, const int* in_sizes, int n_in,
                              void* d_out, int out_size, void* d_ws, size_t ws_size,
                              hipStream_t stream)
{
  (void)in_sizes; (void)n_in; (void)out_size; (void)ws_size;
  const float* feats   = (const float*)d_in[0];
  const float* w_fp    = (const float*)d_in[2];
  const float* b_fp    = (const float*)d_in[3];
  const float* w_si    = (const float*)d_in[4];
  const float* b_si    = (const float*)d_in[5];
  const float* w_ih1   = (const float*)d_in[6];
  const float* w_hh1   = (const float*)d_in[7];
  const float* b_ih1   = (const float*)d_in[8];
  const float* b_hh1   = (const float*)d_in[9];
  const float* w_ih2   = (const float*)d_in[10];
  const float* w_hh2   = (const float*)d_in[11];
  const float* b_ih2   = (const float*)d_in[12];
  const float* b_hh2   = (const float*)d_in[13];
  const float* w_q     = (const float*)d_in[14];
  const float* b_q     = (const float*)d_in[15];
  const float* w_cov   = (const float*)d_in[16];
  const float* b_cov   = (const float*)d_in[17];
  const float* w_cum   = (const float*)d_in[18];
  const float* b_cum   = (const float*)d_in[19];
  const float* w_logit = (const float*)d_in[20];
  const float* b_logit = (const float*)d_in[21];
  const float* w_c1    = (const float*)d_in[22];
  const float* b_c1    = (const float*)d_in[23];
  const float* w_c2    = (const float*)d_in[24];
  const float* b_c2    = (const float*)d_in[25];
  float* ws  = (float*)d_ws;
  float* out = (float*)d_out;

  init_k<<<1, 256, 0, stream>>>(ws);
  state0_k<<<16, 256, 0, stream>>>(feats, w_si, b_si, ws);
  precomp_k<<<dim3(17,16), 256, 0, stream>>>(feats, w_ih2, b_ih2, ws);
  persist_k<<<256, 256, 0, stream>>>(feats, w_fp, b_fp, w_ih1, b_ih1,
                                     w_hh1, b_hh1, w_hh2, b_hh2,
                                     w_q, b_q, w_cov, b_cov, w_cum, b_cum,
                                     w_logit, b_logit, w_c1, b_c1, w_c2, b_c2,
                                     ws, out);
}